// Round 2
// baseline (980.291 us; speedup 1.0000x reference)
//
#include <hip/hip_runtime.h>
#include <math.h>

// Problem constants (fixed by setup_inputs; select_top_r == 8 always)
// B0=2048 tokens, C=512, P=32 past, R=8 selected, H=8 heads, DH=64, HID=256

static __device__ __forceinline__ float4 ld4(const float* p) { return *(const float4*)p; }

static __device__ __forceinline__ float gelu_exact(float x) {
  return 0.5f * x * (1.0f + erff(x * 0.70710678118654752f));
}

// ---------------------------------------------------------------------------
// Wqk = Wq @ Wk^T   (512x512; Wqk[c][j] = sum_i Wq[c][i]*Wk[j][i])
// ---------------------------------------------------------------------------
__global__ __launch_bounds__(256) void wqk_kernel(const float* __restrict__ Wq,
                                                  const float* __restrict__ Wk,
                                                  float* __restrict__ Wqk) {
  __shared__ float Aq[32][36];
  __shared__ float Bk[32][36];
  const int tid = threadIdx.x;
  const int c0 = blockIdx.y << 5, j0 = blockIdx.x << 5;
  const int r = tid >> 3, ic = (tid & 7) << 2;
  const int ty = tid >> 4, tx = tid & 15;
  float acc00 = 0.f, acc01 = 0.f, acc10 = 0.f, acc11 = 0.f;
  for (int i0 = 0; i0 < 512; i0 += 32) {
    float4 a = ld4(Wq + (size_t)(c0 + r) * 512 + i0 + ic);
    float4 b = ld4(Wk + (size_t)(j0 + r) * 512 + i0 + ic);
    Aq[r][ic] = a.x; Aq[r][ic + 1] = a.y; Aq[r][ic + 2] = a.z; Aq[r][ic + 3] = a.w;
    Bk[r][ic] = b.x; Bk[r][ic + 1] = b.y; Bk[r][ic + 2] = b.z; Bk[r][ic + 3] = b.w;
    __syncthreads();
#pragma unroll
    for (int i = 0; i < 32; ++i) {
      float a0 = Aq[ty * 2][i], a1 = Aq[ty * 2 + 1][i];
      float b0 = Bk[tx * 2][i], b1 = Bk[tx * 2 + 1][i];
      acc00 += a0 * b0; acc01 += a0 * b1; acc10 += a1 * b0; acc11 += a1 * b1;
    }
    __syncthreads();
  }
  Wqk[(size_t)(c0 + ty * 2) * 512 + j0 + tx * 2]     = acc00;
  Wqk[(size_t)(c0 + ty * 2) * 512 + j0 + tx * 2 + 1] = acc01;
  Wqk[(size_t)(c0 + ty * 2 + 1) * 512 + j0 + tx * 2]     = acc10;
  Wqk[(size_t)(c0 + ty * 2 + 1) * 512 + j0 + tx * 2 + 1] = acc11;
}

// ---------------------------------------------------------------------------
// Generic 64x64x16 fp32 tiled GEMM with mode-specific A-gather & epilogue.
// MODE 0: Y = (hidden+pe0) @ [Wq|Wk|Wv|Wqk]            (C=Y, ldc=2048)
// MODE 1: kvsel = (cached[idx]+pe[idx]) @ [Wk|Wv]      (gather rows)
// MODE 2: h = gelu([q|ksel|vsel] @ W1 + b1)
// MODE 3: kvsel += g*s*(h @ W2[:, :1024] + b2[:1024])  (in-place delta)
// MODE 4: out = ctx @ Wo + bo
// ---------------------------------------------------------------------------
template <int MODE>
__global__ __launch_bounds__(256) void gemm_k(
    const float* __restrict__ A, const float* __restrict__ A2,
    const float* __restrict__ Bp0, const float* __restrict__ Bp1,
    const float* __restrict__ Bp2, const float* __restrict__ Bp3,
    float* __restrict__ C, const float* __restrict__ pe,
    const float* __restrict__ bias, const float* __restrict__ sgv,
    const int* __restrict__ idxv, int K, int lda, int ldb, int ldc) {
  __shared__ float As[16][68];
  __shared__ float Bs[16][68];
  const int tid = threadIdx.x;
  const int rm = blockIdx.y << 6;
  const int cn = blockIdx.x << 6;

  const float* Bp; int cb;
  if constexpr (MODE == 0) {
    int seg = cn >> 9;
    Bp = (seg == 0) ? Bp0 : (seg == 1) ? Bp1 : (seg == 2) ? Bp2 : Bp3;
    cb = cn & 511;
  } else if constexpr (MODE == 1) {
    Bp = (cn >> 9) ? Bp1 : Bp0; cb = cn & 511;
  } else {
    Bp = Bp0; cb = cn;
  }

  const int tx = tid & 15, ty = tid >> 4;
  const int ar = tid >> 2, ak = (tid & 3) << 2;   // A staging: row ar, k-off ak
  const int bk = tid >> 4, bn = (tid & 15) << 2;  // B staging: k-row bk, col bn
  const int arow = rm + ar;

  const float* Ap = nullptr; const float* pep = nullptr;
  if constexpr (MODE == 0) {
    Ap = A + (size_t)arow * 512; pep = pe;  // pe row 0
  } else if constexpr (MODE == 1) {
    int p = idxv[arow];
    Ap = A + ((size_t)(arow >> 3) * 32 + p) * 512;
    pep = pe + (size_t)p * 512;
  } else if constexpr (MODE == 2) {
    // two-source, handled in loop (A = kvsel, A2 = Y)
  } else {
    Ap = A + (size_t)arow * lda;
  }

  float acc[4][4] = {};
  const int nk = K >> 4;
  for (int kt = 0; kt < nk; ++kt) {
    const int k0 = (kt << 4) + ak;
    float4 av;
    if constexpr (MODE == 0 || MODE == 1) {
      float4 x = ld4(Ap + k0);
      float4 p4 = ld4(pep + k0);
      av = make_float4(x.x + p4.x, x.y + p4.y, x.z + p4.z, x.w + p4.w);
    } else if constexpr (MODE == 2) {
      if (k0 < 512) av = ld4(A2 + (size_t)(arow >> 3) * 2048 + k0);
      else          av = ld4(A + (size_t)arow * 1024 + (k0 - 512));
    } else {
      av = ld4(Ap + k0);
    }
    As[ak + 0][ar] = av.x; As[ak + 1][ar] = av.y;
    As[ak + 2][ar] = av.z; As[ak + 3][ar] = av.w;

    if constexpr (MODE == 3) {
      // W2 rows are 1026 floats: 16B-misaligned for odd k -> scalar loads
      const float* bp = Bp + (size_t)((kt << 4) + bk) * ldb + cb + bn;
      Bs[bk][bn] = bp[0]; Bs[bk][bn + 1] = bp[1];
      Bs[bk][bn + 2] = bp[2]; Bs[bk][bn + 3] = bp[3];
    } else {
      float4 bv = ld4(Bp + (size_t)((kt << 4) + bk) * ldb + cb + bn);
      *(float4*)&Bs[bk][bn] = bv;
    }
    __syncthreads();
#pragma unroll
    for (int kk = 0; kk < 16; ++kk) {
      float4 a = *(const float4*)&As[kk][ty << 2];
      float4 b = *(const float4*)&Bs[kk][tx << 2];
      acc[0][0] += a.x * b.x; acc[0][1] += a.x * b.y; acc[0][2] += a.x * b.z; acc[0][3] += a.x * b.w;
      acc[1][0] += a.y * b.x; acc[1][1] += a.y * b.y; acc[1][2] += a.y * b.z; acc[1][3] += a.y * b.w;
      acc[2][0] += a.z * b.x; acc[2][1] += a.z * b.y; acc[2][2] += a.z * b.z; acc[2][3] += a.z * b.w;
      acc[3][0] += a.w * b.x; acc[3][1] += a.w * b.y; acc[3][2] += a.w * b.z; acc[3][3] += a.w * b.w;
    }
    __syncthreads();
  }

  const int row0 = rm + (ty << 2), col0 = cn + (tx << 2);
#pragma unroll
  for (int i = 0; i < 4; ++i) {
    const int row = row0 + i;
    float* cp = C + (size_t)row * ldc + col0;
    if constexpr (MODE == 0 || MODE == 1) {
      *(float4*)cp = make_float4(acc[i][0], acc[i][1], acc[i][2], acc[i][3]);
    } else if constexpr (MODE == 2) {
      float4 bb = ld4(bias + col0);
      *(float4*)cp = make_float4(gelu_exact(acc[i][0] + bb.x), gelu_exact(acc[i][1] + bb.y),
                                 gelu_exact(acc[i][2] + bb.z), gelu_exact(acc[i][3] + bb.w));
    } else if constexpr (MODE == 3) {
      float s = sgv[row * 2], g = sgv[row * 2 + 1];
      float gs = g * s;
      float4 bb = ld4(bias + col0);
      float4 old = ld4(cp);
      *(float4*)cp = make_float4(old.x + gs * (acc[i][0] + bb.x),
                                 old.y + gs * (acc[i][1] + bb.y),
                                 old.z + gs * (acc[i][2] + bb.z),
                                 old.w + gs * (acc[i][3] + bb.w));
    } else {
      float4 bb = ld4(bias + col0);
      *(float4*)cp = make_float4(acc[i][0] + bb.x, acc[i][1] + bb.y,
                                 acc[i][2] + bb.z, acc[i][3] + bb.w);
    }
  }
}

// ---------------------------------------------------------------------------
// scores[p] = qk . (cached[b0,p]+pe[p]);  top-8 (ties -> lower index, like lax.top_k)
// ---------------------------------------------------------------------------
__global__ __launch_bounds__(256) void score_topk(const float* __restrict__ Y,
                                                  const float* __restrict__ cached,
                                                  const float* __restrict__ pe,
                                                  int* __restrict__ idxv) {
  __shared__ float sc[32];
  const int b0 = blockIdx.x;
  const int tid = threadIdx.x;
  const int wave = tid >> 6, lane = tid & 63;
  const int off = lane << 3;
  const float* qk = Y + (size_t)b0 * 2048 + 1536;
  float4 q0 = ld4(qk + off);
  float4 q1 = ld4(qk + off + 4);
  for (int i = 0; i < 8; ++i) {
    const int p = (wave << 3) + i;
    const float* cp = cached + ((size_t)b0 * 32 + p) * 512 + off;
    const float* pp = pe + (size_t)p * 512 + off;
    float4 c0 = ld4(cp), c1 = ld4(cp + 4);
    float4 e0 = ld4(pp), e1 = ld4(pp + 4);
    float s = (c0.x + e0.x) * q0.x + (c0.y + e0.y) * q0.y +
              (c0.z + e0.z) * q0.z + (c0.w + e0.w) * q0.w +
              (c1.x + e1.x) * q1.x + (c1.y + e1.y) * q1.y +
              (c1.z + e1.z) * q1.z + (c1.w + e1.w) * q1.w;
#pragma unroll
    for (int d = 32; d > 0; d >>= 1) s += __shfl_xor(s, d);
    if (lane == 0) sc[p] = s;
  }
  __syncthreads();
  if (tid == 0) {
    for (int r = 0; r < 8; ++r) {
      float best = -INFINITY; int bi = 0;
      for (int p = 0; p < 32; ++p) {
        float v = sc[p];
        if (v > best) { best = v; bi = p; }
      }
      idxv[b0 * 8 + r] = bi;
      sc[bi] = -INFINITY;
    }
  }
}

// ---------------------------------------------------------------------------
// Per-row s (softplus) and g (sigmoid) from W2 cols 1024/1025
// ---------------------------------------------------------------------------
__global__ __launch_bounds__(256) void sg_kernel(const float* __restrict__ hb,
                                                 const float* __restrict__ W2,
                                                 const float* __restrict__ b2,
                                                 float* __restrict__ sgv) {
  __shared__ float w0[256], w1[256];
  const int tid = threadIdx.x;
  w0[tid] = W2[(size_t)tid * 1026 + 1024];
  w1[tid] = W2[(size_t)tid * 1026 + 1025];
  __syncthreads();
  const int wave = tid >> 6, lane = tid & 63;
  const int m = (blockIdx.x << 2) + wave;
  const int k4 = lane << 2;
  float4 hv = ld4(hb + (size_t)m * 256 + k4);
  float a0 = hv.x * w0[k4] + hv.y * w0[k4 + 1] + hv.z * w0[k4 + 2] + hv.w * w0[k4 + 3];
  float a1 = hv.x * w1[k4] + hv.y * w1[k4 + 1] + hv.z * w1[k4 + 2] + hv.w * w1[k4 + 3];
#pragma unroll
  for (int d = 32; d > 0; d >>= 1) { a0 += __shfl_xor(a0, d); a1 += __shfl_xor(a1, d); }
  if (lane == 0) {
    float t0 = a0 + b2[1024];
    float t1 = a1 + b2[1025];
    float s = (t0 > 0.f ? t0 + log1pf(expf(-t0)) : log1pf(expf(t0))) + 1e-5f;
    float g = 1.f / (1.f + expf(-t1));
    sgv[m * 2] = s; sgv[m * 2 + 1] = g;
  }
}

// ---------------------------------------------------------------------------
// 9-key attention per token -> ctx
// ---------------------------------------------------------------------------
__global__ __launch_bounds__(64) void attn_kernel(const float* __restrict__ Y,
                                                  const float* __restrict__ kvsel,
                                                  float* __restrict__ ctx) {
  __shared__ float kb[9][512];
  __shared__ float vb[9][512];
  __shared__ float qb[512];
  __shared__ float lg[72];
  __shared__ float aw[8][9];
  const int b0 = blockIdx.x;
  const int tid = threadIdx.x;
  const int c0 = tid << 3;
  const float* yrow = Y + (size_t)b0 * 2048;
  *(float4*)&qb[c0] = ld4(yrow + c0);
  *(float4*)&qb[c0 + 4] = ld4(yrow + c0 + 4);
  *(float4*)&kb[8][c0] = ld4(yrow + 512 + c0);
  *(float4*)&kb[8][c0 + 4] = ld4(yrow + 512 + c0 + 4);
  *(float4*)&vb[8][c0] = ld4(yrow + 1024 + c0);
  *(float4*)&vb[8][c0 + 4] = ld4(yrow + 1024 + c0 + 4);
#pragma unroll
  for (int r = 0; r < 8; ++r) {
    const float* kvrow = kvsel + (size_t)(b0 * 8 + r) * 1024;
    *(float4*)&kb[r][c0] = ld4(kvrow + c0);
    *(float4*)&kb[r][c0 + 4] = ld4(kvrow + c0 + 4);
    *(float4*)&vb[r][c0] = ld4(kvrow + 512 + c0);
    *(float4*)&vb[r][c0 + 4] = ld4(kvrow + 512 + c0 + 4);
  }
  __syncthreads();
  for (int id = tid; id < 72; id += 64) {
    const int h = id / 9, k = id - h * 9;
    const float* qh = qb + h * 64;
    const float* kh = &kb[k][h * 64];
    float s = 0.f;
#pragma unroll
    for (int d = 0; d < 64; ++d) s += qh[d] * kh[d];
    lg[id] = s * 0.125f;  // DH^-0.5
  }
  __syncthreads();
  if (tid < 8) {
    float m = -INFINITY;
#pragma unroll
    for (int k = 0; k < 9; ++k) m = fmaxf(m, lg[tid * 9 + k]);
    float e[9]; float sum = 0.f;
#pragma unroll
    for (int k = 0; k < 9; ++k) { e[k] = expf(lg[tid * 9 + k] - m); sum += e[k]; }
    float inv = 1.f / sum;
#pragma unroll
    for (int k = 0; k < 9; ++k) aw[tid][k] = e[k] * inv;
  }
  __syncthreads();
  const int h = c0 >> 6;
  float4 a0 = make_float4(0, 0, 0, 0), a1 = make_float4(0, 0, 0, 0);
#pragma unroll
  for (int k = 0; k < 9; ++k) {
    float w = aw[h][k];
    float4 v0 = *(const float4*)&vb[k][c0];
    float4 v1 = *(const float4*)&vb[k][c0 + 4];
    a0.x += w * v0.x; a0.y += w * v0.y; a0.z += w * v0.z; a0.w += w * v0.w;
    a1.x += w * v1.x; a1.y += w * v1.y; a1.z += w * v1.z; a1.w += w * v1.w;
  }
  float* cr = ctx + (size_t)b0 * 512 + c0;
  *(float4*)cr = a0;
  *(float4*)(cr + 4) = a1;
}

// ---------------------------------------------------------------------------
extern "C" void kernel_launch(void* const* d_in, const int* in_sizes, int n_in,
                              void* d_out, int out_size, void* d_ws, size_t ws_size,
                              hipStream_t stream) {
  const float* hidden = (const float*)d_in[0];
  const float* cached = (const float*)d_in[1];
  const float* Wq = (const float*)d_in[2];
  const float* Wk = (const float*)d_in[3];
  const float* Wv = (const float*)d_in[4];
  const float* Wo = (const float*)d_in[5];
  const float* bo = (const float*)d_in[6];
  const float* W1 = (const float*)d_in[7];
  const float* b1 = (const float*)d_in[8];
  const float* W2 = (const float*)d_in[9];
  const float* b2 = (const float*)d_in[10];
  const float* pe = (const float*)d_in[11];
  // d_in[12] = select_top_r == 8 (fixed by problem)

  float* ws = (float*)d_ws;
  float* Wqk = ws;                       // 512*512
  float* Y = Wqk + 512 * 512;            // 2048*2048  [q|k_now|v_now|qk]
  float* kvsel = Y + 2048 * 2048;        // 16384*1024 [k_sel|v_sel]
  float* hbuf = kvsel + 16384 * 1024;    // 16384*256
  float* sgv = hbuf + 16384 * 256;       // 16384*2
  float* ctx = sgv + 16384 * 2;          // 2048*512
  int* idxv = (int*)(ctx + 2048 * 512);  // 16384 ints
  float* out = (float*)d_out;
  (void)in_sizes; (void)n_in; (void)out_size; (void)ws_size;

  // 1. Wqk = Wq @ Wk^T
  wqk_kernel<<<dim3(16, 16), 256, 0, stream>>>(Wq, Wk, Wqk);
  // 2. Y = (hidden + pe0) @ [Wq|Wk|Wv|Wqk]
  gemm_k<0><<<dim3(32, 32), 256, 0, stream>>>(hidden, nullptr, Wq, Wk, Wv, Wqk, Y, pe,
                                              nullptr, nullptr, nullptr, 512, 512, 512, 2048);
  // 3. scores + top-8
  score_topk<<<dim3(2048), 256, 0, stream>>>(Y, cached, pe, idxv);
  // 4. kvsel = gathered past_pos @ [Wk|Wv]
  gemm_k<1><<<dim3(16, 256), 256, 0, stream>>>(cached, nullptr, Wk, Wv, nullptr, nullptr,
                                               kvsel, pe, nullptr, nullptr, idxv, 512, 512, 512, 1024);
  // 5. h = gelu([q|ksel|vsel] @ W1 + b1)
  gemm_k<2><<<dim3(4, 256), 256, 0, stream>>>(kvsel, Y, W1, nullptr, nullptr, nullptr,
                                              hbuf, nullptr, b1, nullptr, nullptr, 1536, 1024, 256, 256);
  // 6. per-row s,g
  sg_kernel<<<dim3(4096), 256, 0, stream>>>(hbuf, W2, b2, sgv);
  // 7. kvsel += g*s*(h @ W2[:, :1024] + b2[:1024])
  gemm_k<3><<<dim3(16, 256), 256, 0, stream>>>(hbuf, nullptr, W2, nullptr, nullptr, nullptr,
                                               kvsel, nullptr, b2, sgv, nullptr, 256, 256, 1026, 1024);
  // 8. attention -> ctx
  attn_kernel<<<dim3(2048), 64, 0, stream>>>(Y, kvsel, ctx);
  // 9. out = ctx @ Wo + bo
  gemm_k<4><<<dim3(8, 32), 256, 0, stream>>>(ctx, nullptr, Wo, nullptr, nullptr, nullptr,
                                             out, nullptr, bo, nullptr, nullptr, 512, 512, 512, 512);
}

// Round 3
// 569.104 us; speedup vs baseline: 1.7225x; 1.7225x over previous
//
#include <hip/hip_runtime.h>
#include <math.h>

// B0=2048 tokens, C=512, P=32 past, R=8 selected, H=8 heads, DH=64, HID=256
// Strategy: fp32 exact path for top-k scores (Wqk trick); bf16 MFMA for the
// 4 heavy GEMMs (42 of 44 GF).

typedef __attribute__((ext_vector_type(8))) __bf16 bf16x8;
typedef __attribute__((ext_vector_type(4))) float f32x4;

static __device__ __forceinline__ float4 ld4(const float* p) { return *(const float4*)p; }

static __device__ __forceinline__ float gelu_exact(float x) {
  return 0.5f * x * (1.0f + erff(x * 0.70710678118654752f));
}
static __device__ __forceinline__ unsigned short f2bf(float f) {  // RNE
  unsigned int u = __float_as_uint(f);
  u = (u + 0x7fffu + ((u >> 16) & 1u)) >> 16;
  return (unsigned short)u;
}
static __device__ __forceinline__ float bf2f(unsigned short h) {
  return __uint_as_float(((unsigned int)h) << 16);
}
static __device__ __forceinline__ unsigned int pk2(float a, float b) {
  return (unsigned int)f2bf(a) | ((unsigned int)f2bf(b) << 16);
}
static __device__ __forceinline__ void gld16(const void* g, void* l) {
  __builtin_amdgcn_global_load_lds((const __attribute__((address_space(1))) void*)g,
                                   (__attribute__((address_space(3))) void*)l, 16, 0, 0);
}

// ---------------------------------------------------------------------------
// Wqk = Wq @ Wk^T (fp32, feeds the exact score path)
// ---------------------------------------------------------------------------
__global__ __launch_bounds__(256) void wqk_kernel(const float* __restrict__ Wq,
                                                  const float* __restrict__ Wk,
                                                  float* __restrict__ Wqk) {
  __shared__ float Aq[32][36];
  __shared__ float Bk[32][36];
  const int tid = threadIdx.x;
  const int c0 = blockIdx.y << 5, j0 = blockIdx.x << 5;
  const int r = tid >> 3, ic = (tid & 7) << 2;
  const int ty = tid >> 4, tx = tid & 15;
  float acc00 = 0.f, acc01 = 0.f, acc10 = 0.f, acc11 = 0.f;
  for (int i0 = 0; i0 < 512; i0 += 32) {
    float4 a = ld4(Wq + (size_t)(c0 + r) * 512 + i0 + ic);
    float4 b = ld4(Wk + (size_t)(j0 + r) * 512 + i0 + ic);
    Aq[r][ic] = a.x; Aq[r][ic + 1] = a.y; Aq[r][ic + 2] = a.z; Aq[r][ic + 3] = a.w;
    Bk[r][ic] = b.x; Bk[r][ic + 1] = b.y; Bk[r][ic + 2] = b.z; Bk[r][ic + 3] = b.w;
    __syncthreads();
#pragma unroll
    for (int i = 0; i < 32; ++i) {
      float a0 = Aq[ty * 2][i], a1 = Aq[ty * 2 + 1][i];
      float b0 = Bk[tx * 2][i], b1 = Bk[tx * 2 + 1][i];
      acc00 += a0 * b0; acc01 += a0 * b1; acc10 += a1 * b0; acc11 += a1 * b1;
    }
    __syncthreads();
  }
  Wqk[(size_t)(c0 + ty * 2) * 512 + j0 + tx * 2]     = acc00;
  Wqk[(size_t)(c0 + ty * 2) * 512 + j0 + tx * 2 + 1] = acc01;
  Wqk[(size_t)(c0 + ty * 2 + 1) * 512 + j0 + tx * 2]     = acc10;
  Wqk[(size_t)(c0 + ty * 2 + 1) * 512 + j0 + tx * 2 + 1] = acc11;
}

// ---------------------------------------------------------------------------
// fp32 64x64x16 tiled GEMM (kept for qk score path MODE 0 and out MODE 4)
// ---------------------------------------------------------------------------
template <int MODE>
__global__ __launch_bounds__(256) void gemm_k(
    const float* __restrict__ A, const float* __restrict__ A2,
    const float* __restrict__ Bp0, const float* __restrict__ Bp1,
    const float* __restrict__ Bp2, const float* __restrict__ Bp3,
    float* __restrict__ C, const float* __restrict__ pe,
    const float* __restrict__ bias, const float* __restrict__ sgv,
    const int* __restrict__ idxv, int K, int lda, int ldb, int ldc) {
  __shared__ float As[16][68];
  __shared__ float Bs[16][68];
  const int tid = threadIdx.x;
  const int rm = blockIdx.y << 6;
  const int cn = blockIdx.x << 6;

  const float* Bp; int cb;
  if constexpr (MODE == 0) {
    int seg = cn >> 9;
    Bp = (seg == 0) ? Bp0 : (seg == 1) ? Bp1 : (seg == 2) ? Bp2 : Bp3;
    cb = cn & 511;
  } else {
    Bp = Bp0; cb = cn;
  }

  const int tx = tid & 15, ty = tid >> 4;
  const int ar = tid >> 2, ak = (tid & 3) << 2;
  const int bk = tid >> 4, bn = (tid & 15) << 2;
  const int arow = rm + ar;

  const float* Ap = nullptr; const float* pep = nullptr;
  if constexpr (MODE == 0) {
    Ap = A + (size_t)arow * 512; pep = pe;  // pe row 0
  } else {
    Ap = A + (size_t)arow * lda;
  }

  float acc[4][4] = {};
  const int nk = K >> 4;
  for (int kt = 0; kt < nk; ++kt) {
    const int k0 = (kt << 4) + ak;
    float4 av;
    if constexpr (MODE == 0) {
      float4 x = ld4(Ap + k0);
      float4 p4 = ld4(pep + k0);
      av = make_float4(x.x + p4.x, x.y + p4.y, x.z + p4.z, x.w + p4.w);
    } else {
      av = ld4(Ap + k0);
    }
    As[ak + 0][ar] = av.x; As[ak + 1][ar] = av.y;
    As[ak + 2][ar] = av.z; As[ak + 3][ar] = av.w;
    float4 bv = ld4(Bp + (size_t)((kt << 4) + bk) * ldb + cb + bn);
    *(float4*)&Bs[bk][bn] = bv;
    __syncthreads();
#pragma unroll
    for (int kk = 0; kk < 16; ++kk) {
      float4 a = *(const float4*)&As[kk][ty << 2];
      float4 b = *(const float4*)&Bs[kk][tx << 2];
      acc[0][0] += a.x * b.x; acc[0][1] += a.x * b.y; acc[0][2] += a.x * b.z; acc[0][3] += a.x * b.w;
      acc[1][0] += a.y * b.x; acc[1][1] += a.y * b.y; acc[1][2] += a.y * b.z; acc[1][3] += a.y * b.w;
      acc[2][0] += a.z * b.x; acc[2][1] += a.z * b.y; acc[2][2] += a.z * b.z; acc[2][3] += a.z * b.w;
      acc[3][0] += a.w * b.x; acc[3][1] += a.w * b.y; acc[3][2] += a.w * b.z; acc[3][3] += a.w * b.w;
    }
    __syncthreads();
  }

  const int row0 = rm + (ty << 2), col0 = cn + (tx << 2);
#pragma unroll
  for (int i = 0; i < 4; ++i) {
    const int row = row0 + i;
    float* cp = C + (size_t)row * ldc + col0;
    if constexpr (MODE == 0) {
      *(float4*)cp = make_float4(acc[i][0], acc[i][1], acc[i][2], acc[i][3]);
    } else {
      float4 bb = ld4(bias + col0);
      *(float4*)cp = make_float4(acc[i][0] + bb.x, acc[i][1] + bb.y,
                                 acc[i][2] + bb.z, acc[i][3] + bb.w);
    }
  }
}

// ---------------------------------------------------------------------------
// Weight transpose + bf16 convert: D[n][k] = bf16(S[k][n]), S row stride lds_
// ---------------------------------------------------------------------------
__global__ __launch_bounds__(256) void trans_b(const float* __restrict__ S,
                                               unsigned short* __restrict__ D,
                                               int K, int lds_) {
  __shared__ float t[32][33];
  const int kb = blockIdx.y << 5, nb = blockIdx.x << 5;
  const int tx = threadIdx.x & 31, ty8 = threadIdx.x >> 5;
  for (int yy = ty8; yy < 32; yy += 8)
    t[yy][tx] = S[(size_t)(kb + yy) * lds_ + nb + tx];
  __syncthreads();
  for (int yy = ty8; yy < 32; yy += 8)
    D[(size_t)(nb + yy) * K + kb + tx] = f2bf(t[tx][yy]);
}

// ---------------------------------------------------------------------------
// bf16 MFMA GEMM: BM=BN=128, BK=32, 256 threads (4 waves, 64x64/wave).
// SRC 0: A row m = hidden[m] + pe[0]           (fp32 reg-stage)
// SRC 1: A row m = cached[idxv[m]] + pe[idx&31] (fp32 reg-stage, gather)
// SRC 2: A = [ q(Yh bf16, k<512) | kvf fp32 (k>=512) ]
// SRC 3: A = hb bf16 (global_load_lds)
// EP 0: store Cf fp32 + Ch bf16 | EP 1: Cf only | EP 2: gelu(+bias)->Ch bf16
// EP 3: Cf += g*s*(acc+bias)  (gated delta RMW)
// ---------------------------------------------------------------------------
template <int SRC, int EP>
__global__ __launch_bounds__(256) void bgemm(
    const float* __restrict__ Af, const unsigned short* __restrict__ Ah,
    const unsigned short* __restrict__ Bt,
    float* __restrict__ Cf, unsigned short* __restrict__ Ch,
    const float* __restrict__ pe, const float* __restrict__ bias,
    const float* __restrict__ sgv, const int* __restrict__ idxv,
    const int K, const int ldc) {
  __shared__ unsigned short As[4096];  // [128 rows][32 k]
  __shared__ unsigned short Bs[4096];  // [128 cols][32 k]
  const int tid = threadIdx.x;
  const int lane = tid & 63, w = tid >> 6;
  const int rm = blockIdx.y << 7, cn = blockIdx.x << 7;
  const int srow = tid >> 2, skb = (tid & 3) << 3;
  const int m0 = rm + srow, m1 = m0 + 64;

  const float* af0 = nullptr; const float* af1 = nullptr;
  const float* pe0 = nullptr; const float* pe1 = nullptr;
  const unsigned short* ah0 = nullptr; const unsigned short* ah1 = nullptr;
  if constexpr (SRC == 0) {
    af0 = Af + (size_t)m0 * 512 + skb;  af1 = Af + (size_t)m1 * 512 + skb;
    pe0 = pe + skb;                     pe1 = pe + skb;
  } else if constexpr (SRC == 1) {
    const int g0 = idxv[m0], g1 = idxv[m1];
    af0 = Af + (size_t)g0 * 512 + skb;  af1 = Af + (size_t)g1 * 512 + skb;
    pe0 = pe + (size_t)(g0 & 31) * 512 + skb;
    pe1 = pe + (size_t)(g1 & 31) * 512 + skb;
  } else if constexpr (SRC == 2) {
    ah0 = Ah + (size_t)(m0 >> 3) * 1536 + skb;
    ah1 = Ah + (size_t)(m1 >> 3) * 1536 + skb;
    af0 = Af + (size_t)m0 * 1024 + skb;
    af1 = Af + (size_t)m1 * 1024 + skb;
  } else {
    ah0 = Ah + (size_t)m0 * 256 + skb;
    ah1 = Ah + (size_t)m1 * 256 + skb;
  }
  const unsigned short* bt0 = Bt + (size_t)(cn + srow) * K + skb;
  const unsigned short* bt1 = Bt + (size_t)(cn + srow + 64) * K + skb;

  unsigned short* asD0 = As + (w << 9);          // wave-uniform bases
  unsigned short* asD1 = As + 2048 + (w << 9);
  unsigned short* bsD0 = Bs + (w << 9);
  unsigned short* bsD1 = Bs + 2048 + (w << 9);
  unsigned short* awr0 = As + srow * 32 + skb;   // reg-stage ds_write addrs
  unsigned short* awr1 = As + (srow + 64) * 32 + skb;

  const int ar = (((w >> 1) << 6) + (lane & 15)) * 32 + ((lane >> 4) << 3);
  const int br = (((w & 1) << 6) + (lane & 15)) * 32 + ((lane >> 4) << 3);

  f32x4 acc[4][4];
#pragma unroll
  for (int i = 0; i < 4; ++i)
#pragma unroll
    for (int j = 0; j < 4; ++j) acc[i][j] = (f32x4){0.f, 0.f, 0.f, 0.f};

  const int nk = K >> 5;
  for (int kt = 0; kt < nk; ++kt) {
    const int k0 = kt << 5;
    float4 r0a, r0b, r1a, r1b, q0a, q0b, q1a, q1b;
    bool regstage = false;
    if constexpr (SRC == 0 || SRC == 1) {
      regstage = true;
      r0a = ld4(af0 + k0); r0b = ld4(af0 + k0 + 4);
      r1a = ld4(af1 + k0); r1b = ld4(af1 + k0 + 4);
      q0a = ld4(pe0 + k0); q0b = ld4(pe0 + k0 + 4);
      q1a = ld4(pe1 + k0); q1b = ld4(pe1 + k0 + 4);
    } else if constexpr (SRC == 2) {
      if (k0 >= 512) {
        regstage = true;
        r0a = ld4(af0 + k0 - 512); r0b = ld4(af0 + k0 - 508);
        r1a = ld4(af1 + k0 - 512); r1b = ld4(af1 + k0 - 508);
        q0a = q0b = q1a = q1b = make_float4(0.f, 0.f, 0.f, 0.f);
      }
    }
    __syncthreads();  // all waves done reading previous tiles
    if constexpr (SRC == 3) {
      gld16(ah0 + k0, asD0); gld16(ah1 + k0, asD1);
    } else if constexpr (SRC == 2) {
      if (k0 < 512) { gld16(ah0 + k0, asD0); gld16(ah1 + k0, asD1); }
    }
    if (regstage) {
      int4 wv0, wv1;
      wv0.x = pk2(r0a.x + q0a.x, r0a.y + q0a.y);
      wv0.y = pk2(r0a.z + q0a.z, r0a.w + q0a.w);
      wv0.z = pk2(r0b.x + q0b.x, r0b.y + q0b.y);
      wv0.w = pk2(r0b.z + q0b.z, r0b.w + q0b.w);
      wv1.x = pk2(r1a.x + q1a.x, r1a.y + q1a.y);
      wv1.y = pk2(r1a.z + q1a.z, r1a.w + q1a.w);
      wv1.z = pk2(r1b.x + q1b.x, r1b.y + q1b.y);
      wv1.w = pk2(r1b.z + q1b.z, r1b.w + q1b.w);
      *(int4*)awr0 = wv0;
      *(int4*)awr1 = wv1;
    }
    gld16(bt0 + k0, bsD0); gld16(bt1 + k0, bsD1);
    __syncthreads();  // staging complete (barrier drains vmcnt+lgkmcnt)
    bf16x8 av[4], bv[4];
#pragma unroll
    for (int i = 0; i < 4; ++i) av[i] = *(const bf16x8*)(As + ar + i * 512);
#pragma unroll
    for (int j = 0; j < 4; ++j) bv[j] = *(const bf16x8*)(Bs + br + j * 512);
#pragma unroll
    for (int i = 0; i < 4; ++i)
#pragma unroll
      for (int j = 0; j < 4; ++j)
        acc[i][j] = __builtin_amdgcn_mfma_f32_16x16x32_bf16(av[i], bv[j], acc[i][j], 0, 0, 0);
  }

  // epilogue: D[(lane>>4)*4+r][lane&15] per 16x16 frag (m89-verified)
  const int row0 = rm + ((w >> 1) << 6) + (((lane >> 4) & 3) << 2);
  const int col0 = cn + ((w & 1) << 6) + (lane & 15);
#pragma unroll
  for (int j = 0; j < 4; ++j) {
    const int col = col0 + j * 16;
    float bcol = 0.f;
    if constexpr (EP == 2 || EP == 3) bcol = bias[col];
#pragma unroll
    for (int i = 0; i < 4; ++i) {
      const int rowb = row0 + i * 16;
#pragma unroll
      for (int r = 0; r < 4; ++r) {
        const int rr = rowb + r;
        const float v = acc[i][j][r];
        if constexpr (EP == 0) {
          Cf[(size_t)rr * ldc + col] = v;
          Ch[(size_t)rr * ldc + col] = f2bf(v);
        } else if constexpr (EP == 1) {
          Cf[(size_t)rr * ldc + col] = v;
        } else if constexpr (EP == 2) {
          Ch[(size_t)rr * ldc + col] = f2bf(gelu_exact(v + bcol));
        } else {
          const float s = sgv[2 * rr], g = sgv[2 * rr + 1];
          Cf[(size_t)rr * ldc + col] += g * s * (v + bcol);
        }
      }
    }
  }
}

// ---------------------------------------------------------------------------
// scores[p] = qk . (cached[b0,p]+pe[p]); top-8 -> GLOBAL cache row indices
// ---------------------------------------------------------------------------
__global__ __launch_bounds__(256) void score_topk(const float* __restrict__ QK,
                                                  const float* __restrict__ cached,
                                                  const float* __restrict__ pe,
                                                  int* __restrict__ idxv) {
  __shared__ float sc[32];
  const int b0 = blockIdx.x;
  const int tid = threadIdx.x;
  const int wave = tid >> 6, lane = tid & 63;
  const int off = lane << 3;
  const float* qk = QK + (size_t)b0 * 512;
  float4 q0 = ld4(qk + off);
  float4 q1 = ld4(qk + off + 4);
  for (int i = 0; i < 8; ++i) {
    const int p = (wave << 3) + i;
    const float* cp = cached + ((size_t)b0 * 32 + p) * 512 + off;
    const float* pp = pe + (size_t)p * 512 + off;
    float4 c0 = ld4(cp), c1 = ld4(cp + 4);
    float4 e0 = ld4(pp), e1 = ld4(pp + 4);
    float s = (c0.x + e0.x) * q0.x + (c0.y + e0.y) * q0.y +
              (c0.z + e0.z) * q0.z + (c0.w + e0.w) * q0.w +
              (c1.x + e1.x) * q1.x + (c1.y + e1.y) * q1.y +
              (c1.z + e1.z) * q1.z + (c1.w + e1.w) * q1.w;
#pragma unroll
    for (int d = 32; d > 0; d >>= 1) s += __shfl_xor(s, d);
    if (lane == 0) sc[p] = s;
  }
  __syncthreads();
  if (tid == 0) {
    for (int r = 0; r < 8; ++r) {
      float best = -INFINITY; int bi = 0;
      for (int p = 0; p < 32; ++p) {
        float v = sc[p];
        if (v > best) { best = v; bi = p; }
      }
      idxv[b0 * 8 + r] = b0 * 32 + bi;  // global row into cached
      sc[bi] = -INFINITY;
    }
  }
}

// ---------------------------------------------------------------------------
// Per-row s (softplus) and g (sigmoid) from W2 cols 1024/1025; h is bf16
// ---------------------------------------------------------------------------
__global__ __launch_bounds__(256) void sg_kernel(const unsigned short* __restrict__ hb,
                                                 const float* __restrict__ W2,
                                                 const float* __restrict__ b2,
                                                 float* __restrict__ sgv) {
  __shared__ float w0[256], w1[256];
  const int tid = threadIdx.x;
  w0[tid] = W2[(size_t)tid * 1026 + 1024];
  w1[tid] = W2[(size_t)tid * 1026 + 1025];
  __syncthreads();
  const int wave = tid >> 6, lane = tid & 63;
  const int m = (blockIdx.x << 2) + wave;
  const int k4 = lane << 2;
  ushort4 hv = *(const ushort4*)(hb + (size_t)m * 256 + k4);
  const float h0 = bf2f(hv.x), h1 = bf2f(hv.y), h2 = bf2f(hv.z), h3 = bf2f(hv.w);
  float a0 = h0 * w0[k4] + h1 * w0[k4 + 1] + h2 * w0[k4 + 2] + h3 * w0[k4 + 3];
  float a1 = h0 * w1[k4] + h1 * w1[k4 + 1] + h2 * w1[k4 + 2] + h3 * w1[k4 + 3];
#pragma unroll
  for (int d = 32; d > 0; d >>= 1) { a0 += __shfl_xor(a0, d); a1 += __shfl_xor(a1, d); }
  if (lane == 0) {
    float t0 = a0 + b2[1024];
    float t1 = a1 + b2[1025];
    float s = (t0 > 0.f ? t0 + log1pf(expf(-t0)) : log1pf(expf(t0))) + 1e-5f;
    float g = 1.f / (1.f + expf(-t1));
    sgv[m * 2] = s; sgv[m * 2 + 1] = g;
  }
}

// ---------------------------------------------------------------------------
// 9-key attention per token -> ctx  (Yf layout: [q|k_now|v_now], ld 1536)
// ---------------------------------------------------------------------------
__global__ __launch_bounds__(64) void attn_kernel(const float* __restrict__ Yf,
                                                  const float* __restrict__ kvsel,
                                                  float* __restrict__ ctx) {
  __shared__ float kb[9][512];
  __shared__ float vb[9][512];
  __shared__ float qb[512];
  __shared__ float lg[72];
  __shared__ float aw[8][9];
  const int b0 = blockIdx.x;
  const int tid = threadIdx.x;
  const int c0 = tid << 3;
  const float* yrow = Yf + (size_t)b0 * 1536;
  *(float4*)&qb[c0] = ld4(yrow + c0);
  *(float4*)&qb[c0 + 4] = ld4(yrow + c0 + 4);
  *(float4*)&kb[8][c0] = ld4(yrow + 512 + c0);
  *(float4*)&kb[8][c0 + 4] = ld4(yrow + 512 + c0 + 4);
  *(float4*)&vb[8][c0] = ld4(yrow + 1024 + c0);
  *(float4*)&vb[8][c0 + 4] = ld4(yrow + 1024 + c0 + 4);
#pragma unroll
  for (int r = 0; r < 8; ++r) {
    const float* kvrow = kvsel + (size_t)(b0 * 8 + r) * 1024;
    *(float4*)&kb[r][c0] = ld4(kvrow + c0);
    *(float4*)&kb[r][c0 + 4] = ld4(kvrow + c0 + 4);
    *(float4*)&vb[r][c0] = ld4(kvrow + 512 + c0);
    *(float4*)&vb[r][c0 + 4] = ld4(kvrow + 512 + c0 + 4);
  }
  __syncthreads();
  for (int id = tid; id < 72; id += 64) {
    const int h = id / 9, k = id - h * 9;
    const float* qh = qb + h * 64;
    const float* kh = &kb[k][h * 64];
    float s = 0.f;
#pragma unroll
    for (int d = 0; d < 64; ++d) s += qh[d] * kh[d];
    lg[id] = s * 0.125f;
  }
  __syncthreads();
  if (tid < 8) {
    float m = -INFINITY;
#pragma unroll
    for (int k = 0; k < 9; ++k) m = fmaxf(m, lg[tid * 9 + k]);
    float e[9]; float sum = 0.f;
#pragma unroll
    for (int k = 0; k < 9; ++k) { e[k] = expf(lg[tid * 9 + k] - m); sum += e[k]; }
    float inv = 1.f / sum;
#pragma unroll
    for (int k = 0; k < 9; ++k) aw[tid][k] = e[k] * inv;
  }
  __syncthreads();
  const int h = c0 >> 6;
  float4 a0 = make_float4(0, 0, 0, 0), a1 = make_float4(0, 0, 0, 0);
#pragma unroll
  for (int k = 0; k < 9; ++k) {
    float wgt = aw[h][k];
    float4 v0 = *(const float4*)&vb[k][c0];
    float4 v1 = *(const float4*)&vb[k][c0 + 4];
    a0.x += wgt * v0.x; a0.y += wgt * v0.y; a0.z += wgt * v0.z; a0.w += wgt * v0.w;
    a1.x += wgt * v1.x; a1.y += wgt * v1.y; a1.z += wgt * v1.z; a1.w += wgt * v1.w;
  }
  float* cr = ctx + (size_t)b0 * 512 + c0;
  *(float4*)cr = a0;
  *(float4*)(cr + 4) = a1;
}

// ---------------------------------------------------------------------------
extern "C" void kernel_launch(void* const* d_in, const int* in_sizes, int n_in,
                              void* d_out, int out_size, void* d_ws, size_t ws_size,
                              hipStream_t stream) {
  const float* hidden = (const float*)d_in[0];
  const float* cached = (const float*)d_in[1];
  const float* Wq = (const float*)d_in[2];
  const float* Wk = (const float*)d_in[3];
  const float* Wv = (const float*)d_in[4];
  const float* Wo = (const float*)d_in[5];
  const float* bo = (const float*)d_in[6];
  const float* W1 = (const float*)d_in[7];
  const float* b1 = (const float*)d_in[8];
  const float* W2 = (const float*)d_in[9];
  const float* b2 = (const float*)d_in[10];
  const float* pe = (const float*)d_in[11];

  float* ws = (float*)d_ws;
  float* Wqk  = ws;                      // 512*512
  float* qk   = Wqk + 262144;            // 2048*512
  float* Yf   = qk + 1048576;            // 2048*1536  [q|k_now|v_now] fp32
  float* kvf  = Yf + 3145728;            // 16384*1024 [k_sel|v_sel] fp32
  float* ctx  = kvf + 16777216;          // 2048*512
  float* sgv  = ctx + 1048576;           // 16384*2
  int* idxv   = (int*)(sgv + 32768);     // 16384
  unsigned short* Wqkvt = (unsigned short*)(idxv + 16384);  // [1536][512] bf16
  unsigned short* W1t = Wqkvt + 786432;  // [256][1536] bf16
  unsigned short* W2t = W1t + 393216;    // [1024][256] bf16
  unsigned short* Yh  = W2t + 262144;    // 2048*1536 bf16
  unsigned short* hb  = Yh + 3145728;    // 16384*256 bf16
  float* out = (float*)d_out;
  (void)in_sizes; (void)n_in; (void)out_size; (void)ws_size;

  // weight prep (bf16 transposes)
  trans_b<<<dim3(16, 16), 256, 0, stream>>>(Wq, Wqkvt, 512, 512);
  trans_b<<<dim3(16, 16), 256, 0, stream>>>(Wk, Wqkvt + 262144, 512, 512);
  trans_b<<<dim3(16, 16), 256, 0, stream>>>(Wv, Wqkvt + 524288, 512, 512);
  trans_b<<<dim3(8, 48), 256, 0, stream>>>(W1, W1t, 1536, 256);
  trans_b<<<dim3(32, 8), 256, 0, stream>>>(W2, W2t, 256, 1026);
  // exact score path (fp32): Wqk, qk = (hidden+pe0) @ Wqk, top-8
  wqk_kernel<<<dim3(16, 16), 256, 0, stream>>>(Wq, Wk, Wqk);
  gemm_k<0><<<dim3(8, 32), 256, 0, stream>>>(hidden, nullptr, Wqk, Wqk, Wqk, Wqk, qk, pe,
                                             nullptr, nullptr, nullptr, 512, 512, 512, 512);
  score_topk<<<dim3(2048), 256, 0, stream>>>(qk, cached, pe, idxv);
  // bf16 MFMA GEMMs
  bgemm<0, 0><<<dim3(12, 16), 256, 0, stream>>>(hidden, nullptr, Wqkvt, Yf, Yh, pe,
                                                nullptr, nullptr, nullptr, 512, 1536);
  bgemm<1, 1><<<dim3(8, 128), 256, 0, stream>>>(cached, nullptr, Wqkvt + 262144, kvf, nullptr,
                                                pe, nullptr, nullptr, idxv, 512, 1024);
  bgemm<2, 2><<<dim3(2, 128), 256, 0, stream>>>(kvf, Yh, W1t, nullptr, hb,
                                                nullptr, b1, nullptr, nullptr, 1536, 256);
  sg_kernel<<<dim3(4096), 256, 0, stream>>>(hb, W2, b2, sgv);
  bgemm<3, 3><<<dim3(8, 128), 256, 0, stream>>>(nullptr, hb, W2t, kvf, nullptr,
                                                nullptr, b2, sgv, nullptr, 256, 1024);
  // attention + output projection (fp32)
  attn_kernel<<<dim3(2048), 64, 0, stream>>>(Yf, kvf, ctx);
  gemm_k<4><<<dim3(8, 32), 256, 0, stream>>>(ctx, nullptr, Wo, nullptr, nullptr, nullptr,
                                             out, nullptr, bo, nullptr, nullptr, 512, 512, 512, 512);
}

// Round 4
// 493.309 us; speedup vs baseline: 1.9872x; 1.1536x over previous
//
#include <hip/hip_runtime.h>
#include <math.h>

// B0=2048 tokens, C=512, P=32 past, R=8 selected, H=8 heads, DH=64, HID=256
// fp32 exact path for top-k scores (Wqk trick); bf16 MFMA (m97 structure,
// pure global_load_lds staging) for the 5 heavy GEMMs.

typedef __attribute__((ext_vector_type(8))) __bf16 bf16x8;
typedef __attribute__((ext_vector_type(4))) float f32x4;
typedef unsigned short u16;
typedef unsigned int u32;

static __device__ __forceinline__ float4 ld4(const float* p) { return *(const float4*)p; }
static __device__ __forceinline__ float gelu_exact(float x) {
  return 0.5f * x * (1.0f + erff(x * 0.70710678118654752f));
}
static __device__ __forceinline__ u16 f2bf(float f) {  // RNE
  u32 u = __float_as_uint(f);
  u = (u + 0x7fffu + ((u >> 16) & 1u)) >> 16;
  return (u16)u;
}
static __device__ __forceinline__ float bf2f(u16 h) {
  return __uint_as_float(((u32)h) << 16);
}
static __device__ __forceinline__ u32 pk2(float a, float b) {
  return (u32)f2bf(a) | ((u32)f2bf(b) << 16);
}
static __device__ __forceinline__ void gld16(const void* g, void* l) {
  __builtin_amdgcn_global_load_lds((const __attribute__((address_space(1))) void*)g,
                                   (__attribute__((address_space(3))) void*)l, 16, 0, 0);
}

// ---------------------------------------------------------------------------
// Fused weight prep: bf16 transposes of Wq|Wk|Wv -> Wqkvt, W1 -> W1t,
// W2[:, :1024] -> W2t, Wo -> Wot.  One 32x32 tile per block.
// ---------------------------------------------------------------------------
__global__ __launch_bounds__(256) void prep_w(
    const float* __restrict__ Wq, const float* __restrict__ Wk,
    const float* __restrict__ Wv, const float* __restrict__ W1,
    const float* __restrict__ W2, const float* __restrict__ Wo,
    u16* __restrict__ Wqkvt, u16* __restrict__ W1t,
    u16* __restrict__ W2t, u16* __restrict__ Wot) {
  __shared__ float t[32][33];
  const int b = blockIdx.x;
  const float* S; u16* D; int lds_, Kd, nx, t0;
  if (b < 256)       { S = Wq; D = Wqkvt;              lds_ = 512;  Kd = 512;  nx = 16; t0 = 0; }
  else if (b < 512)  { S = Wk; D = Wqkvt + 512 * 512;  lds_ = 512;  Kd = 512;  nx = 16; t0 = 256; }
  else if (b < 768)  { S = Wv; D = Wqkvt + 1024 * 512; lds_ = 512;  Kd = 512;  nx = 16; t0 = 512; }
  else if (b < 1152) { S = W1; D = W1t;                lds_ = 256;  Kd = 1536; nx = 8;  t0 = 768; }
  else if (b < 1408) { S = W2; D = W2t;                lds_ = 1026; Kd = 256;  nx = 32; t0 = 1152; }
  else               { S = Wo; D = Wot;                lds_ = 512;  Kd = 512;  nx = 16; t0 = 1408; }
  const int tile = b - t0;
  const int n0 = (tile % nx) << 5, k0 = (tile / nx) << 5;
  const int tx = threadIdx.x & 31, ty8 = threadIdx.x >> 5;
  for (int yy = ty8; yy < 32; yy += 8)
    t[yy][tx] = S[(size_t)(k0 + yy) * lds_ + n0 + tx];
  __syncthreads();
  for (int yy = ty8; yy < 32; yy += 8)
    D[(size_t)(n0 + yy) * Kd + k0 + tx] = f2bf(t[tx][yy]);
}

// ---------------------------------------------------------------------------
// Wqk = Wq @ Wk^T (fp32 exact, feeds the score path)
// ---------------------------------------------------------------------------
__global__ __launch_bounds__(256) void wqk_kernel(const float* __restrict__ Wq,
                                                  const float* __restrict__ Wk,
                                                  float* __restrict__ Wqk) {
  __shared__ float Aq[32][36];
  __shared__ float Bk[32][36];
  const int tid = threadIdx.x;
  const int c0 = blockIdx.y << 5, j0 = blockIdx.x << 5;
  const int r = tid >> 3, ic = (tid & 7) << 2;
  const int ty = tid >> 4, tx = tid & 15;
  float acc00 = 0.f, acc01 = 0.f, acc10 = 0.f, acc11 = 0.f;
  for (int i0 = 0; i0 < 512; i0 += 32) {
    float4 a = ld4(Wq + (size_t)(c0 + r) * 512 + i0 + ic);
    float4 b = ld4(Wk + (size_t)(j0 + r) * 512 + i0 + ic);
    Aq[r][ic] = a.x; Aq[r][ic + 1] = a.y; Aq[r][ic + 2] = a.z; Aq[r][ic + 3] = a.w;
    Bk[r][ic] = b.x; Bk[r][ic + 1] = b.y; Bk[r][ic + 2] = b.z; Bk[r][ic + 3] = b.w;
    __syncthreads();
#pragma unroll
    for (int i = 0; i < 32; ++i) {
      float a0 = Aq[ty * 2][i], a1 = Aq[ty * 2 + 1][i];
      float b0 = Bk[tx * 2][i], b1 = Bk[tx * 2 + 1][i];
      acc00 += a0 * b0; acc01 += a0 * b1; acc10 += a1 * b0; acc11 += a1 * b1;
    }
    __syncthreads();
  }
  Wqk[(size_t)(c0 + ty * 2) * 512 + j0 + tx * 2]     = acc00;
  Wqk[(size_t)(c0 + ty * 2) * 512 + j0 + tx * 2 + 1] = acc01;
  Wqk[(size_t)(c0 + ty * 2 + 1) * 512 + j0 + tx * 2]     = acc10;
  Wqk[(size_t)(c0 + ty * 2 + 1) * 512 + j0 + tx * 2 + 1] = acc11;
}

// ---------------------------------------------------------------------------
// qk = (hidden + pe0) @ Wqk   (fp32 exact, 2048x512x512)
// ---------------------------------------------------------------------------
__global__ __launch_bounds__(256) void qk_gemm(const float* __restrict__ A,
                                               const float* __restrict__ B,
                                               float* __restrict__ C,
                                               const float* __restrict__ pe) {
  __shared__ float As[16][68];
  __shared__ float Bs[16][68];
  const int tid = threadIdx.x;
  const int rm = blockIdx.y << 6, cn = blockIdx.x << 6;
  const int tx = tid & 15, ty = tid >> 4;
  const int ar = tid >> 2, ak = (tid & 3) << 2;
  const int bk = tid >> 4, bn = (tid & 15) << 2;
  const float* Ap = A + (size_t)(rm + ar) * 512;
  float acc[4][4] = {};
  for (int kt = 0; kt < 32; ++kt) {
    const int k0 = (kt << 4) + ak;
    float4 x = ld4(Ap + k0);
    float4 p4 = ld4(pe + k0);
    As[ak + 0][ar] = x.x + p4.x; As[ak + 1][ar] = x.y + p4.y;
    As[ak + 2][ar] = x.z + p4.z; As[ak + 3][ar] = x.w + p4.w;
    *(float4*)&Bs[bk][bn] = ld4(B + (size_t)((kt << 4) + bk) * 512 + cn + bn);
    __syncthreads();
#pragma unroll
    for (int kk = 0; kk < 16; ++kk) {
      float4 a = *(const float4*)&As[kk][ty << 2];
      float4 b = *(const float4*)&Bs[kk][tx << 2];
      acc[0][0] += a.x * b.x; acc[0][1] += a.x * b.y; acc[0][2] += a.x * b.z; acc[0][3] += a.x * b.w;
      acc[1][0] += a.y * b.x; acc[1][1] += a.y * b.y; acc[1][2] += a.y * b.z; acc[1][3] += a.y * b.w;
      acc[2][0] += a.z * b.x; acc[2][1] += a.z * b.y; acc[2][2] += a.z * b.z; acc[2][3] += a.z * b.w;
      acc[3][0] += a.w * b.x; acc[3][1] += a.w * b.y; acc[3][2] += a.w * b.z; acc[3][3] += a.w * b.w;
    }
    __syncthreads();
  }
  const int row0 = rm + (ty << 2), col0 = cn + (tx << 2);
#pragma unroll
  for (int i = 0; i < 4; ++i)
    *(float4*)(C + (size_t)(row0 + i) * 512 + col0) =
        make_float4(acc[i][0], acc[i][1], acc[i][2], acc[i][3]);
}

// ---------------------------------------------------------------------------
// scores + top-8 -> GLOBAL cache row indices
// ---------------------------------------------------------------------------
__global__ __launch_bounds__(256) void score_topk(const float* __restrict__ QK,
                                                  const float* __restrict__ cached,
                                                  const float* __restrict__ pe,
                                                  int* __restrict__ idxv) {
  __shared__ float sc[32];
  const int b0 = blockIdx.x;
  const int tid = threadIdx.x;
  const int wave = tid >> 6, lane = tid & 63;
  const int off = lane << 3;
  const float* qk = QK + (size_t)b0 * 512;
  float4 q0 = ld4(qk + off);
  float4 q1 = ld4(qk + off + 4);
  for (int i = 0; i < 8; ++i) {
    const int p = (wave << 3) + i;
    const float* cp = cached + ((size_t)b0 * 32 + p) * 512 + off;
    const float* pp = pe + (size_t)p * 512 + off;
    float4 c0 = ld4(cp), c1 = ld4(cp + 4);
    float4 e0 = ld4(pp), e1 = ld4(pp + 4);
    float s = (c0.x + e0.x) * q0.x + (c0.y + e0.y) * q0.y +
              (c0.z + e0.z) * q0.z + (c0.w + e0.w) * q0.w +
              (c1.x + e1.x) * q1.x + (c1.y + e1.y) * q1.y +
              (c1.z + e1.z) * q1.z + (c1.w + e1.w) * q1.w;
#pragma unroll
    for (int d = 32; d > 0; d >>= 1) s += __shfl_xor(s, d);
    if (lane == 0) sc[p] = s;
  }
  __syncthreads();
  if (tid == 0) {
    for (int r = 0; r < 8; ++r) {
      float best = -INFINITY; int bi = 0;
      for (int p = 0; p < 32; ++p) {
        float v = sc[p];
        if (v > best) { best = v; bi = p; }
      }
      idxv[b0 * 8 + r] = b0 * 32 + bi;
      sc[bi] = -INFINITY;
    }
  }
}

// ---------------------------------------------------------------------------
// prep_a: xh = bf16(hidden+pe0) [2048][512]; gsel = bf16(cached[idx]+pe) [16384][512]
// one row per wave, 4 rows per block
// ---------------------------------------------------------------------------
__global__ __launch_bounds__(256) void prep_a(const float* __restrict__ hidden,
                                              const float* __restrict__ cached,
                                              const float* __restrict__ pe,
                                              const int* __restrict__ idxv,
                                              u16* __restrict__ xh,
                                              u16* __restrict__ gsel) {
  const int row = (blockIdx.x << 2) + (threadIdx.x >> 6);
  const int lane = threadIdx.x & 63;
  const int off = lane << 3;
  const float* src; const float* ps; u16* dst;
  if (row < 2048) {
    src = hidden + (size_t)row * 512; ps = pe; dst = xh + (size_t)row * 512;
  } else {
    const int m = row - 2048;
    const int g = idxv[m];
    src = cached + (size_t)g * 512;
    ps = pe + (size_t)(g & 31) * 512;
    dst = gsel + (size_t)m * 512;
  }
  float4 a = ld4(src + off), b = ld4(src + off + 4);
  float4 p = ld4(ps + off), q = ld4(ps + off + 4);
  int4 o;
  o.x = pk2(a.x + p.x, a.y + p.y);
  o.y = pk2(a.z + p.z, a.w + p.w);
  o.z = pk2(b.x + q.x, b.y + q.y);
  o.w = pk2(b.z + q.z, b.w + q.w);
  *(int4*)(dst + off) = o;
}

// ---------------------------------------------------------------------------
// bf16 MFMA GEMM, m97 structure: BM=BN=128, BK=32, 256 thr, global_load_lds.
// CAT 0: A = Ah [M][K] bf16.   CAT 1 (mlp1): k<512 from qh[m>>3], else kvh[m].
// EP 0: Yf fp32(ldc) + qh bf16 (col<512)   EP 1: kvf fp32 + kvh bf16
// EP 2: hb = bf16(gelu(v+bias))            EP 3: kvf += g*s*(v+bias)
// EP 4: out = v + bias (fp32)
// ---------------------------------------------------------------------------
template <int CAT, int EP>
__global__ __launch_bounds__(256) void bgemm(
    const u16* __restrict__ Ah, const u16* __restrict__ Ah2,
    const u16* __restrict__ Bt,
    float* __restrict__ Cf, u16* __restrict__ Ch,
    const float* __restrict__ bias, const float* __restrict__ sgv,
    const int K, const int ldc) {
  __shared__ u16 As[4096];  // [128][32]
  __shared__ u16 Bs[4096];
  const int tid = threadIdx.x, lane = tid & 63, w = tid >> 6;
  const int rm = blockIdx.y << 7, cn = blockIdx.x << 7;
  const int srow = tid >> 2, skoff = (tid & 3) << 3;

  const u16 *a0, *a1, *q0 = nullptr, *q1 = nullptr;
  if constexpr (CAT == 0) {
    a0 = Ah + (size_t)(rm + srow) * K + skoff;
    a1 = Ah + (size_t)(rm + 64 + srow) * K + skoff;
  } else {
    const int m0 = rm + srow, m1 = rm + 64 + srow;
    q0 = Ah + (size_t)(m0 >> 3) * 512 + skoff;
    q1 = Ah + (size_t)(m1 >> 3) * 512 + skoff;
    a0 = Ah2 + (size_t)m0 * 1024 + skoff;
    a1 = Ah2 + (size_t)m1 * 1024 + skoff;
  }
  const u16* b0 = Bt + (size_t)(cn + srow) * K + skoff;
  const u16* b1 = Bt + (size_t)(cn + 64 + srow) * K + skoff;

  u16* aD0 = As + (w << 9); u16* aD1 = As + 2048 + (w << 9);
  u16* bD0 = Bs + (w << 9); u16* bD1 = Bs + 2048 + (w << 9);
  const int arb = ((((w >> 1) << 6) + (lane & 15)) << 5) + ((lane >> 4) << 3);
  const int brb = ((((w & 1) << 6) + (lane & 15)) << 5) + ((lane >> 4) << 3);

  f32x4 acc[4][4];
#pragma unroll
  for (int i = 0; i < 4; ++i)
#pragma unroll
    for (int j = 0; j < 4; ++j) acc[i][j] = (f32x4){0.f, 0.f, 0.f, 0.f};

  const int nk = K >> 5;
  for (int kt = 0; kt < nk; ++kt) {
    const int ko = kt << 5;
    if (kt) __syncthreads();
    if constexpr (CAT == 0) {
      gld16(a0 + ko, aD0); gld16(a1 + ko, aD1);
    } else {
      if (kt < 16) { gld16(q0 + ko, aD0); gld16(q1 + ko, aD1); }
      else         { gld16(a0 + ko - 512, aD0); gld16(a1 + ko - 512, aD1); }
    }
    gld16(b0 + ko, bD0); gld16(b1 + ko, bD1);
    __syncthreads();
    bf16x8 av[4], bv[4];
#pragma unroll
    for (int i = 0; i < 4; ++i) av[i] = *(const bf16x8*)(As + arb + (i << 9));
#pragma unroll
    for (int j = 0; j < 4; ++j) bv[j] = *(const bf16x8*)(Bs + brb + (j << 9));
#pragma unroll
    for (int i = 0; i < 4; ++i)
#pragma unroll
      for (int j = 0; j < 4; ++j)
        acc[i][j] = __builtin_amdgcn_mfma_f32_16x16x32_bf16(av[i], bv[j], acc[i][j], 0, 0, 0);
  }

  const int row0 = rm + ((w >> 1) << 6) + ((lane >> 4) << 2);
  const int col0 = cn + ((w & 1) << 6) + (lane & 15);
#pragma unroll
  for (int j = 0; j < 4; ++j) {
    const int col = col0 + (j << 4);
    float bcol = 0.f;
    if constexpr (EP == 2 || EP == 3 || EP == 4) bcol = bias[col];
#pragma unroll
    for (int i = 0; i < 4; ++i) {
#pragma unroll
      for (int r = 0; r < 4; ++r) {
        const int rr = row0 + (i << 4) + r;
        const float v = acc[i][j][r];
        if constexpr (EP == 0) {
          Cf[(size_t)rr * ldc + col] = v;
          if (col < 512) Ch[(size_t)rr * 512 + col] = f2bf(v);
        } else if constexpr (EP == 1) {
          Cf[(size_t)rr * ldc + col] = v;
          Ch[(size_t)rr * ldc + col] = f2bf(v);
        } else if constexpr (EP == 2) {
          Ch[(size_t)rr * ldc + col] = f2bf(gelu_exact(v + bcol));
        } else if constexpr (EP == 3) {
          const float s = sgv[2 * rr], g = sgv[2 * rr + 1];
          Cf[(size_t)rr * ldc + col] += g * s * (v + bcol);
        } else {
          Cf[(size_t)rr * ldc + col] = v + bcol;
        }
      }
    }
  }
}

// ---------------------------------------------------------------------------
// Per-row s (softplus) / g (sigmoid) from W2 cols 1024/1025; h is bf16
// ---------------------------------------------------------------------------
__global__ __launch_bounds__(256) void sg_kernel(const u16* __restrict__ hb,
                                                 const float* __restrict__ W2,
                                                 const float* __restrict__ b2,
                                                 float* __restrict__ sgv) {
  __shared__ float w0[256], w1[256];
  const int tid = threadIdx.x;
  w0[tid] = W2[(size_t)tid * 1026 + 1024];
  w1[tid] = W2[(size_t)tid * 1026 + 1025];
  __syncthreads();
  const int wave = tid >> 6, lane = tid & 63;
  const int m = (blockIdx.x << 2) + wave;
  const int k4 = lane << 2;
  ushort4 hv = *(const ushort4*)(hb + (size_t)m * 256 + k4);
  const float h0 = bf2f(hv.x), h1 = bf2f(hv.y), h2 = bf2f(hv.z), h3 = bf2f(hv.w);
  float a0 = h0 * w0[k4] + h1 * w0[k4 + 1] + h2 * w0[k4 + 2] + h3 * w0[k4 + 3];
  float a1 = h0 * w1[k4] + h1 * w1[k4 + 1] + h2 * w1[k4 + 2] + h3 * w1[k4 + 3];
#pragma unroll
  for (int d = 32; d > 0; d >>= 1) { a0 += __shfl_xor(a0, d); a1 += __shfl_xor(a1, d); }
  if (lane == 0) {
    float t0 = a0 + b2[1024];
    float t1 = a1 + b2[1025];
    float s = (t0 > 0.f ? t0 + log1pf(expf(-t0)) : log1pf(expf(t0))) + 1e-5f;
    float g = 1.f / (1.f + expf(-t1));
    sgv[m * 2] = s; sgv[m * 2 + 1] = g;
  }
}

// ---------------------------------------------------------------------------
// attention: one wave per token, register-only. lane owns 8 dims of head lane>>3.
// ---------------------------------------------------------------------------
__global__ __launch_bounds__(256) void attn2(const float* __restrict__ Yf,
                                             const float* __restrict__ kvf,
                                             u16* __restrict__ ctxh) {
  const int w = threadIdx.x >> 6, lane = threadIdx.x & 63;
  const int b0 = (blockIdx.x << 2) + w;
  const int off = lane << 3;
  const float* yr = Yf + (size_t)b0 * 1536;
  float4 qa = ld4(yr + off), qb = ld4(yr + off + 4);
  float lg[9];
#pragma unroll
  for (int k = 0; k < 9; ++k) {
    const float* kr = (k < 8) ? (kvf + (size_t)(b0 * 8 + k) * 1024 + off)
                              : (yr + 512 + off);
    float4 ka = ld4(kr), kb = ld4(kr + 4);
    float s = qa.x * ka.x + qa.y * ka.y + qa.z * ka.z + qa.w * ka.w +
              qb.x * kb.x + qb.y * kb.y + qb.z * kb.z + qb.w * kb.w;
    s += __shfl_xor(s, 1); s += __shfl_xor(s, 2); s += __shfl_xor(s, 4);
    lg[k] = s * 0.125f;
  }
  float m = lg[0];
#pragma unroll
  for (int k = 1; k < 9; ++k) m = fmaxf(m, lg[k]);
  float sum = 0.f;
#pragma unroll
  for (int k = 0; k < 9; ++k) { lg[k] = expf(lg[k] - m); sum += lg[k]; }
  const float inv = 1.f / sum;
  float c[8] = {0.f, 0.f, 0.f, 0.f, 0.f, 0.f, 0.f, 0.f};
#pragma unroll
  for (int k = 0; k < 9; ++k) {
    const float* vr = (k < 8) ? (kvf + (size_t)(b0 * 8 + k) * 1024 + 512 + off)
                              : (yr + 1024 + off);
    float4 va = ld4(vr), vb = ld4(vr + 4);
    const float wk = lg[k] * inv;
    c[0] += wk * va.x; c[1] += wk * va.y; c[2] += wk * va.z; c[3] += wk * va.w;
    c[4] += wk * vb.x; c[5] += wk * vb.y; c[6] += wk * vb.z; c[7] += wk * vb.w;
  }
  int4 o;
  o.x = pk2(c[0], c[1]); o.y = pk2(c[2], c[3]);
  o.z = pk2(c[4], c[5]); o.w = pk2(c[6], c[7]);
  *(int4*)(ctxh + (size_t)b0 * 512 + off) = o;
}

// ---------------------------------------------------------------------------
extern "C" void kernel_launch(void* const* d_in, const int* in_sizes, int n_in,
                              void* d_out, int out_size, void* d_ws, size_t ws_size,
                              hipStream_t stream) {
  const float* hidden = (const float*)d_in[0];
  const float* cached = (const float*)d_in[1];
  const float* Wq = (const float*)d_in[2];
  const float* Wk = (const float*)d_in[3];
  const float* Wv = (const float*)d_in[4];
  const float* Wo = (const float*)d_in[5];
  const float* bo = (const float*)d_in[6];
  const float* W1 = (const float*)d_in[7];
  const float* b1 = (const float*)d_in[8];
  const float* W2 = (const float*)d_in[9];
  const float* b2 = (const float*)d_in[10];
  const float* pe = (const float*)d_in[11];

  float* ws = (float*)d_ws;
  float* Wqk = ws;                        // 512*512
  float* qkb = Wqk + 262144;              // 2048*512
  float* Yf  = qkb + 1048576;             // 2048*1536 fp32 [q|k_now|v_now]
  float* kvf = Yf + 3145728;              // 16384*1024 fp32
  float* sgv = kvf + 16777216;            // 16384*2
  int* idxv  = (int*)(sgv + 32768);       // 16384
  u16* Wqkvt = (u16*)(idxv + 16384);      // [1536][512]
  u16* W1t   = Wqkvt + 786432;            // [256][1536]
  u16* W2t   = W1t + 393216;              // [1024][256]
  u16* Wot   = W2t + 262144;              // [512][512]
  u16* xh    = Wot + 262144;              // [2048][512]
  u16* gsel  = xh + 1048576;              // [16384][512]
  u16* qh    = gsel + 8388608;            // [2048][512]
  u16* kvh   = qh + 1048576;              // [16384][1024]
  u16* hb    = kvh + 16777216;            // [16384][256]
  u16* ctxh  = hb + 4194304;              // [2048][512]
  float* out = (float*)d_out;
  (void)in_sizes; (void)n_in; (void)out_size; (void)ws_size;

  // weight prep + exact fp32 score path
  prep_w<<<dim3(1664), 256, 0, stream>>>(Wq, Wk, Wv, W1, W2, Wo, Wqkvt, W1t, W2t, Wot);
  wqk_kernel<<<dim3(16, 16), 256, 0, stream>>>(Wq, Wk, Wqk);
  qk_gemm<<<dim3(8, 32), 256, 0, stream>>>(hidden, Wqk, qkb, pe);
  score_topk<<<dim3(2048), 256, 0, stream>>>(qkb, cached, pe, idxv);
  prep_a<<<dim3(4608), 256, 0, stream>>>(hidden, cached, pe, idxv, xh, gsel);
  // bf16 MFMA GEMMs
  bgemm<0, 0><<<dim3(12, 16), 256, 0, stream>>>(xh, nullptr, Wqkvt, Yf, qh,
                                                nullptr, nullptr, 512, 1536);
  bgemm<0, 1><<<dim3(8, 128), 256, 0, stream>>>(gsel, nullptr, Wqkvt + 512 * 512, kvf, kvh,
                                                nullptr, nullptr, 512, 1024);
  bgemm<1, 2><<<dim3(2, 128), 256, 0, stream>>>(qh, kvh, W1t, nullptr, hb,
                                                b1, nullptr, 1536, 256);
  sg_kernel<<<dim3(4096), 256, 0, stream>>>(hb, W2, b2, sgv);
  bgemm<0, 3><<<dim3(8, 128), 256, 0, stream>>>(hb, nullptr, W2t, kvf, nullptr,
                                                b2, sgv, 256, 1024);
  // attention + output projection
  attn2<<<dim3(512), 256, 0, stream>>>(Yf, kvf, ctxh);
  bgemm<0, 4><<<dim3(4, 16), 256, 0, stream>>>(ctxh, nullptr, Wot, out, nullptr,
                                               bo, nullptr, 512, 512);
}

// Round 5
// 443.025 us; speedup vs baseline: 2.2127x; 1.1135x over previous
//
#include <hip/hip_runtime.h>
#include <math.h>

// B0=2048 tokens, C=512, P=32 past, R=8 selected, H=8 heads, DH=64, HID=256
// fp32 exact path for top-k scores (Wqk trick); everything downstream of
// selection is bf16 (MFMA m97-structure GEMMs, bf16 intermediates only).

typedef __attribute__((ext_vector_type(8))) __bf16 bf16x8;
typedef __attribute__((ext_vector_type(4))) float f32x4;
typedef unsigned short u16;
typedef unsigned int u32;

static __device__ __forceinline__ float4 ld4(const float* p) { return *(const float4*)p; }
static __device__ __forceinline__ float gelu_exact(float x) {
  return 0.5f * x * (1.0f + erff(x * 0.70710678118654752f));
}
static __device__ __forceinline__ u16 f2bf(float f) {  // RNE
  u32 u = __float_as_uint(f);
  u = (u + 0x7fffu + ((u >> 16) & 1u)) >> 16;
  return (u16)u;
}
static __device__ __forceinline__ float bf2f(u16 h) {
  return __uint_as_float(((u32)h) << 16);
}
static __device__ __forceinline__ u32 pk2(float a, float b) {
  return (u32)f2bf(a) | ((u32)f2bf(b) << 16);
}
static __device__ __forceinline__ void ld8bf(const u16* p, float* o) {
  int4 v = *(const int4*)p;
  o[0] = bf2f((u16)((u32)v.x & 0xffffu)); o[1] = bf2f((u16)(((u32)v.x) >> 16));
  o[2] = bf2f((u16)((u32)v.y & 0xffffu)); o[3] = bf2f((u16)(((u32)v.y) >> 16));
  o[4] = bf2f((u16)((u32)v.z & 0xffffu)); o[5] = bf2f((u16)(((u32)v.z) >> 16));
  o[6] = bf2f((u16)((u32)v.w & 0xffffu)); o[7] = bf2f((u16)(((u32)v.w) >> 16));
}
static __device__ __forceinline__ void gld16(const void* g, void* l) {
  __builtin_amdgcn_global_load_lds((const __attribute__((address_space(1))) void*)g,
                                   (__attribute__((address_space(3))) void*)l, 16, 0, 0);
}

// ---------------------------------------------------------------------------
// prep_all: blocks 0-1663 = bf16 weight transposes (Wq|Wk|Wv->Wqkvt, W1->W1t,
// W2[:, :1024]->W2t, Wo->Wot); blocks 1664-1919 = fp32 Wqk = Wq @ Wk^T.
// ---------------------------------------------------------------------------
__global__ __launch_bounds__(256) void prep_all(
    const float* __restrict__ Wq, const float* __restrict__ Wk,
    const float* __restrict__ Wv, const float* __restrict__ W1,
    const float* __restrict__ W2, const float* __restrict__ Wo,
    u16* __restrict__ Wqkvt, u16* __restrict__ W1t,
    u16* __restrict__ W2t, u16* __restrict__ Wot,
    float* __restrict__ Wqk) {
  const int b = blockIdx.x;
  if (b < 1664) {
    __shared__ float t[32][33];
    const float* S; u16* D; int lds_, Kd, nx, t0;
    if (b < 256)       { S = Wq; D = Wqkvt;              lds_ = 512;  Kd = 512;  nx = 16; t0 = 0; }
    else if (b < 512)  { S = Wk; D = Wqkvt + 512 * 512;  lds_ = 512;  Kd = 512;  nx = 16; t0 = 256; }
    else if (b < 768)  { S = Wv; D = Wqkvt + 1024 * 512; lds_ = 512;  Kd = 512;  nx = 16; t0 = 512; }
    else if (b < 1152) { S = W1; D = W1t;                lds_ = 256;  Kd = 1536; nx = 8;  t0 = 768; }
    else if (b < 1408) { S = W2; D = W2t;                lds_ = 1026; Kd = 256;  nx = 32; t0 = 1152; }
    else               { S = Wo; D = Wot;                lds_ = 512;  Kd = 512;  nx = 16; t0 = 1408; }
    const int tile = b - t0;
    const int n0 = (tile % nx) << 5, k0 = (tile / nx) << 5;
    const int tx = threadIdx.x & 31, ty8 = threadIdx.x >> 5;
    for (int yy = ty8; yy < 32; yy += 8)
      t[yy][tx] = S[(size_t)(k0 + yy) * lds_ + n0 + tx];
    __syncthreads();
    for (int yy = ty8; yy < 32; yy += 8)
      D[(size_t)(n0 + yy) * Kd + k0 + tx] = f2bf(t[tx][yy]);
  } else {
    __shared__ float Aq[32][36];
    __shared__ float Bk[32][36];
    const int tile = b - 1664;
    const int c0 = (tile >> 4) << 5, j0 = (tile & 15) << 5;
    const int tid = threadIdx.x;
    const int r = tid >> 3, ic = (tid & 7) << 2;
    const int ty = tid >> 4, tx = tid & 15;
    float a00 = 0.f, a01 = 0.f, a10 = 0.f, a11 = 0.f;
    for (int i0 = 0; i0 < 512; i0 += 32) {
      float4 a = ld4(Wq + (size_t)(c0 + r) * 512 + i0 + ic);
      float4 bb = ld4(Wk + (size_t)(j0 + r) * 512 + i0 + ic);
      Aq[r][ic] = a.x; Aq[r][ic + 1] = a.y; Aq[r][ic + 2] = a.z; Aq[r][ic + 3] = a.w;
      Bk[r][ic] = bb.x; Bk[r][ic + 1] = bb.y; Bk[r][ic + 2] = bb.z; Bk[r][ic + 3] = bb.w;
      __syncthreads();
#pragma unroll
      for (int i = 0; i < 32; ++i) {
        float x0 = Aq[ty * 2][i], x1 = Aq[ty * 2 + 1][i];
        float y0 = Bk[tx * 2][i], y1 = Bk[tx * 2 + 1][i];
        a00 += x0 * y0; a01 += x0 * y1; a10 += x1 * y0; a11 += x1 * y1;
      }
      __syncthreads();
    }
    Wqk[(size_t)(c0 + ty * 2) * 512 + j0 + tx * 2]         = a00;
    Wqk[(size_t)(c0 + ty * 2) * 512 + j0 + tx * 2 + 1]     = a01;
    Wqk[(size_t)(c0 + ty * 2 + 1) * 512 + j0 + tx * 2]     = a10;
    Wqk[(size_t)(c0 + ty * 2 + 1) * 512 + j0 + tx * 2 + 1] = a11;
  }
}

// ---------------------------------------------------------------------------
// qk = (hidden + pe0) @ Wqk   (fp32 exact, 2048x512x512)
// ---------------------------------------------------------------------------
__global__ __launch_bounds__(256) void qk_gemm(const float* __restrict__ A,
                                               const float* __restrict__ B,
                                               float* __restrict__ C,
                                               const float* __restrict__ pe) {
  __shared__ float As[16][68];
  __shared__ float Bs[16][68];
  const int tid = threadIdx.x;
  const int rm = blockIdx.y << 6, cn = blockIdx.x << 6;
  const int tx = tid & 15, ty = tid >> 4;
  const int ar = tid >> 2, ak = (tid & 3) << 2;
  const int bk = tid >> 4, bn = (tid & 15) << 2;
  const float* Ap = A + (size_t)(rm + ar) * 512;
  float acc[4][4] = {};
  for (int kt = 0; kt < 32; ++kt) {
    const int k0 = (kt << 4) + ak;
    float4 x = ld4(Ap + k0);
    float4 p4 = ld4(pe + k0);
    As[ak + 0][ar] = x.x + p4.x; As[ak + 1][ar] = x.y + p4.y;
    As[ak + 2][ar] = x.z + p4.z; As[ak + 3][ar] = x.w + p4.w;
    *(float4*)&Bs[bk][bn] = ld4(B + (size_t)((kt << 4) + bk) * 512 + cn + bn);
    __syncthreads();
#pragma unroll
    for (int kk = 0; kk < 16; ++kk) {
      float4 a = *(const float4*)&As[kk][ty << 2];
      float4 b = *(const float4*)&Bs[kk][tx << 2];
      acc[0][0] += a.x * b.x; acc[0][1] += a.x * b.y; acc[0][2] += a.x * b.z; acc[0][3] += a.x * b.w;
      acc[1][0] += a.y * b.x; acc[1][1] += a.y * b.y; acc[1][2] += a.y * b.z; acc[1][3] += a.y * b.w;
      acc[2][0] += a.z * b.x; acc[2][1] += a.z * b.y; acc[2][2] += a.z * b.z; acc[2][3] += a.z * b.w;
      acc[3][0] += a.w * b.x; acc[3][1] += a.w * b.y; acc[3][2] += a.w * b.z; acc[3][3] += a.w * b.w;
    }
    __syncthreads();
  }
  const int row0 = rm + (ty << 2), col0 = cn + (tx << 2);
#pragma unroll
  for (int i = 0; i < 4; ++i)
    *(float4*)(C + (size_t)(row0 + i) * 512 + col0) =
        make_float4(acc[i][0], acc[i][1], acc[i][2], acc[i][3]);
}

// ---------------------------------------------------------------------------
// score + top-8 + gather (cache rows are L1/L2-hot from the score pass).
// Writes xh = bf16(hidden+pe0), gsel = bf16(cached[sel]+pe[sel]).
// ---------------------------------------------------------------------------
__global__ __launch_bounds__(256) void score_topk_gather(
    const float* __restrict__ QK, const float* __restrict__ cached,
    const float* __restrict__ pe, const float* __restrict__ hidden,
    u16* __restrict__ xh, u16* __restrict__ gsel) {
  __shared__ float sc[32];
  __shared__ int ix[8];
  const int b0 = blockIdx.x;
  const int tid = threadIdx.x;
  const int w = tid >> 6, lane = tid & 63;
  const int off = lane << 3;
  const float* qk = QK + (size_t)b0 * 512;
  float4 q0 = ld4(qk + off);
  float4 q1 = ld4(qk + off + 4);
  for (int i = 0; i < 8; ++i) {
    const int p = (w << 3) + i;
    const float* cp = cached + ((size_t)b0 * 32 + p) * 512 + off;
    const float* pp = pe + (size_t)p * 512 + off;
    float4 c0 = ld4(cp), c1 = ld4(cp + 4);
    float4 e0 = ld4(pp), e1 = ld4(pp + 4);
    float s = (c0.x + e0.x) * q0.x + (c0.y + e0.y) * q0.y +
              (c0.z + e0.z) * q0.z + (c0.w + e0.w) * q0.w +
              (c1.x + e1.x) * q1.x + (c1.y + e1.y) * q1.y +
              (c1.z + e1.z) * q1.z + (c1.w + e1.w) * q1.w;
#pragma unroll
    for (int d = 32; d > 0; d >>= 1) s += __shfl_xor(s, d);
    if (lane == 0) sc[p] = s;
  }
  __syncthreads();
  if (tid == 0) {
    for (int r = 0; r < 8; ++r) {
      float best = -INFINITY; int bi = 0;
      for (int p = 0; p < 32; ++p) {
        float v = sc[p];
        if (v > best) { best = v; bi = p; }
      }
      ix[r] = bi;
      sc[bi] = -INFINITY;
    }
  }
  __syncthreads();
  // gather: wave w -> gsel rows w and w+4; wave 0 also writes xh row
#pragma unroll
  for (int rr = 0; rr < 2; ++rr) {
    const int rsel = w + (rr << 2);
    const int p = ix[rsel];
    const float* cp = cached + ((size_t)b0 * 32 + p) * 512 + off;
    const float* pp = pe + (size_t)p * 512 + off;
    float4 c0 = ld4(cp), c1 = ld4(cp + 4);
    float4 e0 = ld4(pp), e1 = ld4(pp + 4);
    int4 o;
    o.x = pk2(c0.x + e0.x, c0.y + e0.y);
    o.y = pk2(c0.z + e0.z, c0.w + e0.w);
    o.z = pk2(c1.x + e1.x, c1.y + e1.y);
    o.w = pk2(c1.z + e1.z, c1.w + e1.w);
    *(int4*)(gsel + (size_t)(b0 * 8 + rsel) * 512 + off) = o;
  }
  if (w == 0) {
    const float* hp = hidden + (size_t)b0 * 512 + off;
    float4 a = ld4(hp), b = ld4(hp + 4);
    float4 p0 = ld4(pe + off), p1 = ld4(pe + off + 4);
    int4 o;
    o.x = pk2(a.x + p0.x, a.y + p0.y);
    o.y = pk2(a.z + p0.z, a.w + p0.w);
    o.z = pk2(b.x + p1.x, b.y + p1.y);
    o.w = pk2(b.z + p1.z, b.w + p1.w);
    *(int4*)(xh + (size_t)b0 * 512 + off) = o;
  }
}

// ---------------------------------------------------------------------------
// Fused bf16 GEMM #1: blocks 0-1023 kvsel = gsel @ [Wk|Wv]t -> kvh[16384][1024]
//                     blocks 1024-1215 Yh = xh @ [Wq|Wk|Wv]t -> Yh[2048][1536]
// m97 structure: 128x128 tile, BK=32, 256 thr, global_load_lds staging.
// ---------------------------------------------------------------------------
__global__ __launch_bounds__(256) void bgemm_fused1(
    const u16* __restrict__ gsel, const u16* __restrict__ xh,
    const u16* __restrict__ Wqkvt, u16* __restrict__ kvh,
    u16* __restrict__ Yh) {
  __shared__ u16 As[4096];
  __shared__ u16 Bs[4096];
  const int tid = threadIdx.x, lane = tid & 63, w = tid >> 6;
  const int bid = blockIdx.x;
  const int srow = tid >> 2, skoff = (tid & 3) << 3;
  const u16 *a0, *b0; u16* C; int ldc, rm, cn;
  if (bid < 1024) {
    rm = (bid >> 3) << 7; cn = (bid & 7) << 7;
    a0 = gsel + (size_t)(rm + srow) * 512 + skoff;
    b0 = Wqkvt + (size_t)(512 + cn + srow) * 512 + skoff;
    C = kvh; ldc = 1024;
  } else {
    const int b2 = bid - 1024;
    rm = (b2 / 12) << 7; cn = (b2 % 12) << 7;
    a0 = xh + (size_t)(rm + srow) * 512 + skoff;
    b0 = Wqkvt + (size_t)(cn + srow) * 512 + skoff;
    C = Yh; ldc = 1536;
  }
  const u16* a1 = a0 + (size_t)64 * 512;
  const u16* b1 = b0 + (size_t)64 * 512;
  u16* aD0 = As + (w << 9); u16* aD1 = As + 2048 + (w << 9);
  u16* bD0 = Bs + (w << 9); u16* bD1 = Bs + 2048 + (w << 9);
  const int arb = ((((w >> 1) << 6) + (lane & 15)) << 5) + ((lane >> 4) << 3);
  const int brb = ((((w & 1) << 6) + (lane & 15)) << 5) + ((lane >> 4) << 3);
  f32x4 acc[4][4];
#pragma unroll
  for (int i = 0; i < 4; ++i)
#pragma unroll
    for (int j = 0; j < 4; ++j) acc[i][j] = (f32x4){0.f, 0.f, 0.f, 0.f};
  for (int kt = 0; kt < 16; ++kt) {
    const int ko = kt << 5;
    if (kt) __syncthreads();
    gld16(a0 + ko, aD0); gld16(a1 + ko, aD1);
    gld16(b0 + ko, bD0); gld16(b1 + ko, bD1);
    __syncthreads();
    bf16x8 av[4], bv[4];
#pragma unroll
    for (int i = 0; i < 4; ++i) av[i] = *(const bf16x8*)(As + arb + (i << 9));
#pragma unroll
    for (int j = 0; j < 4; ++j) bv[j] = *(const bf16x8*)(Bs + brb + (j << 9));
#pragma unroll
    for (int i = 0; i < 4; ++i)
#pragma unroll
      for (int j = 0; j < 4; ++j)
        acc[i][j] = __builtin_amdgcn_mfma_f32_16x16x32_bf16(av[i], bv[j], acc[i][j], 0, 0, 0);
  }
  const int row0 = rm + ((w >> 1) << 6) + ((lane >> 4) << 2);
  const int col0 = cn + ((w & 1) << 6) + (lane & 15);
#pragma unroll
  for (int j = 0; j < 4; ++j) {
    const int col = col0 + (j << 4);
#pragma unroll
    for (int i = 0; i < 4; ++i)
#pragma unroll
      for (int r = 0; r < 4; ++r)
        C[(size_t)(row0 + (i << 4) + r) * ldc + col] = f2bf(acc[i][j][r]);
  }
}

// ---------------------------------------------------------------------------
// mlp1 + fused sg: h = gelu([q|ksel|vsel] @ W1 + b1) -> hb bf16;
// then per-row s,g from W2 cols 1024/1025 (reads own hb tile, L2-hot).
// BM=64, BN=256 (full width), BK=32, K=1536, 256 thr (4 waves, 64x64 each).
// ---------------------------------------------------------------------------
__global__ __launch_bounds__(256) void mlp1_sg(
    const u16* __restrict__ Yh, const u16* __restrict__ kvh,
    const u16* __restrict__ W1t, const float* __restrict__ b1,
    const float* __restrict__ W2, const float* __restrict__ b2,
    u16* __restrict__ hb, float* __restrict__ sgv) {
  __shared__ u16 As[2048];   // [64][32]
  __shared__ u16 Bs[8192];   // [256][32]
  __shared__ float wa[256], wb[256];
  const int tid = threadIdx.x, lane = tid & 63, w = tid >> 6;
  const int rm = blockIdx.x << 6;
  const int srow = tid >> 2, skoff = (tid & 3) << 3;
  wa[tid] = W2[(size_t)tid * 1026 + 1024];
  wb[tid] = W2[(size_t)tid * 1026 + 1025];
  const int m0 = rm + srow;
  const u16* aq = Yh + (size_t)(m0 >> 3) * 1536 + skoff;   // q of token m>>3
  const u16* akv = kvh + (size_t)m0 * 1024 + skoff;        // k_sel|v_sel
  const u16* bsrc = W1t + (size_t)srow * 1536 + skoff;
  u16* aD = As + (w << 9);
  u16* bD0 = Bs + (w << 9);
  u16* bD1 = Bs + 2048 + (w << 9);
  u16* bD2 = Bs + 4096 + (w << 9);
  u16* bD3 = Bs + 6144 + (w << 9);
  const int arb = ((lane & 15) << 5) + ((lane >> 4) << 3);
  const int brb = (((w << 6) + (lane & 15)) << 5) + ((lane >> 4) << 3);
  f32x4 acc[4][4];
#pragma unroll
  for (int i = 0; i < 4; ++i)
#pragma unroll
    for (int j = 0; j < 4; ++j) acc[i][j] = (f32x4){0.f, 0.f, 0.f, 0.f};
  for (int kt = 0; kt < 48; ++kt) {
    const int ko = kt << 5;
    if (kt) __syncthreads();
    if (kt < 16) gld16(aq + ko, aD);
    else         gld16(akv + ko - 512, aD);
    gld16(bsrc + ko, bD0);
    gld16(bsrc + (size_t)64 * 1536 + ko, bD1);
    gld16(bsrc + (size_t)128 * 1536 + ko, bD2);
    gld16(bsrc + (size_t)192 * 1536 + ko, bD3);
    __syncthreads();
    bf16x8 av[4], bv[4];
#pragma unroll
    for (int i = 0; i < 4; ++i) av[i] = *(const bf16x8*)(As + arb + (i << 9));
#pragma unroll
    for (int j = 0; j < 4; ++j) bv[j] = *(const bf16x8*)(Bs + brb + (j << 9));
#pragma unroll
    for (int i = 0; i < 4; ++i)
#pragma unroll
      for (int j = 0; j < 4; ++j)
        acc[i][j] = __builtin_amdgcn_mfma_f32_16x16x32_bf16(av[i], bv[j], acc[i][j], 0, 0, 0);
  }
  const int row0 = rm + ((lane >> 4) << 2);
  const int col0 = (w << 6) + (lane & 15);
#pragma unroll
  for (int j = 0; j < 4; ++j) {
    const int col = col0 + (j << 4);
    const float bc = b1[col];
#pragma unroll
    for (int i = 0; i < 4; ++i)
#pragma unroll
      for (int r = 0; r < 4; ++r)
        hb[(size_t)(row0 + (i << 4) + r) * 256 + col] = f2bf(gelu_exact(acc[i][j][r] + bc));
  }
  __syncthreads();  // hb tile visible block-wide
  // sg phase: thread group of 4 per row (quarter-rows), shuffle-reduce
  const int row = tid >> 2, q = tid & 3;
  const int rr = rm + row;
  const u16* hp = hb + (size_t)rr * 256 + (q << 6);
  float pa = 0.f, pb = 0.f;
  for (int c = 0; c < 64; c += 8) {
    float h[8]; ld8bf(hp + c, h);
    const int cb = (q << 6) + c;
#pragma unroll
    for (int t = 0; t < 8; ++t) { pa += h[t] * wa[cb + t]; pb += h[t] * wb[cb + t]; }
  }
  pa += __shfl_xor(pa, 1); pa += __shfl_xor(pa, 2);
  pb += __shfl_xor(pb, 1); pb += __shfl_xor(pb, 2);
  if (q == 0) {
    const float t0 = pa + b2[1024];
    const float t1 = pb + b2[1025];
    const float s = (t0 > 0.f ? t0 + log1pf(expf(-t0)) : log1pf(expf(t0))) + 1e-5f;
    const float g = 1.f / (1.f + expf(-t1));
    sgv[2 * rr] = s; sgv[2 * rr + 1] = g;
  }
}

// ---------------------------------------------------------------------------
// delta: kvh += g*s*(hb @ W2t + b2)   (bf16 RMW; 16384x1024x256)
// ---------------------------------------------------------------------------
__global__ __launch_bounds__(256) void bgemm_delta(
    const u16* __restrict__ hb, const u16* __restrict__ W2t,
    u16* __restrict__ kvh, const float* __restrict__ b2,
    const float* __restrict__ sgv) {
  __shared__ u16 As[4096];
  __shared__ u16 Bs[4096];
  const int tid = threadIdx.x, lane = tid & 63, w = tid >> 6;
  const int rm = blockIdx.y << 7, cn = blockIdx.x << 7;
  const int srow = tid >> 2, skoff = (tid & 3) << 3;
  const u16* a0 = hb + (size_t)(rm + srow) * 256 + skoff;
  const u16* a1 = a0 + (size_t)64 * 256;
  const u16* b0 = W2t + (size_t)(cn + srow) * 256 + skoff;
  const u16* b1 = b0 + (size_t)64 * 256;
  u16* aD0 = As + (w << 9); u16* aD1 = As + 2048 + (w << 9);
  u16* bD0 = Bs + (w << 9); u16* bD1 = Bs + 2048 + (w << 9);
  const int arb = ((((w >> 1) << 6) + (lane & 15)) << 5) + ((lane >> 4) << 3);
  const int brb = ((((w & 1) << 6) + (lane & 15)) << 5) + ((lane >> 4) << 3);
  f32x4 acc[4][4];
#pragma unroll
  for (int i = 0; i < 4; ++i)
#pragma unroll
    for (int j = 0; j < 4; ++j) acc[i][j] = (f32x4){0.f, 0.f, 0.f, 0.f};
  for (int kt = 0; kt < 8; ++kt) {
    const int ko = kt << 5;
    if (kt) __syncthreads();
    gld16(a0 + ko, aD0); gld16(a1 + ko, aD1);
    gld16(b0 + ko, bD0); gld16(b1 + ko, bD1);
    __syncthreads();
    bf16x8 av[4], bv[4];
#pragma unroll
    for (int i = 0; i < 4; ++i) av[i] = *(const bf16x8*)(As + arb + (i << 9));
#pragma unroll
    for (int j = 0; j < 4; ++j) bv[j] = *(const bf16x8*)(Bs + brb + (j << 9));
#pragma unroll
    for (int i = 0; i < 4; ++i)
#pragma unroll
      for (int j = 0; j < 4; ++j)
        acc[i][j] = __builtin_amdgcn_mfma_f32_16x16x32_bf16(av[i], bv[j], acc[i][j], 0, 0, 0);
  }
  const int row0 = rm + ((w >> 1) << 6) + ((lane >> 4) << 2);
  const int col0 = cn + ((w & 1) << 6) + (lane & 15);
  float bc[4];
#pragma unroll
  for (int j = 0; j < 4; ++j) bc[j] = b2[col0 + (j << 4)];
#pragma unroll
  for (int i = 0; i < 4; ++i)
#pragma unroll
    for (int r = 0; r < 4; ++r) {
      const int rr = row0 + (i << 4) + r;
      const float gs = sgv[2 * rr] * sgv[2 * rr + 1];
      u16* p = kvh + (size_t)rr * 1024 + col0;
#pragma unroll
      for (int j = 0; j < 4; ++j) {
        const int o = j << 4;
        p[o] = f2bf(bf2f(p[o]) + gs * (acc[i][j][r] + bc[j]));
      }
    }
}

// ---------------------------------------------------------------------------
// attention: one wave per token, register-only, all-bf16 inputs
// ---------------------------------------------------------------------------
__global__ __launch_bounds__(256) void attn2(const u16* __restrict__ Yh,
                                             const u16* __restrict__ kvh,
                                             u16* __restrict__ ctxh) {
  const int w = threadIdx.x >> 6, lane = threadIdx.x & 63;
  const int b0 = (blockIdx.x << 2) + w;
  const int off = lane << 3;
  const u16* yr = Yh + (size_t)b0 * 1536;
  float qv[8]; ld8bf(yr + off, qv);
  float lg[9];
#pragma unroll
  for (int k = 0; k < 9; ++k) {
    const u16* kr = (k < 8) ? (kvh + (size_t)(b0 * 8 + k) * 1024 + off)
                            : (yr + 512 + off);
    float kv[8]; ld8bf(kr, kv);
    float s = qv[0] * kv[0] + qv[1] * kv[1] + qv[2] * kv[2] + qv[3] * kv[3] +
              qv[4] * kv[4] + qv[5] * kv[5] + qv[6] * kv[6] + qv[7] * kv[7];
    s += __shfl_xor(s, 1); s += __shfl_xor(s, 2); s += __shfl_xor(s, 4);
    lg[k] = s * 0.125f;
  }
  float m = lg[0];
#pragma unroll
  for (int k = 1; k < 9; ++k) m = fmaxf(m, lg[k]);
  float sum = 0.f;
#pragma unroll
  for (int k = 0; k < 9; ++k) { lg[k] = expf(lg[k] - m); sum += lg[k]; }
  const float inv = 1.f / sum;
  float c[8] = {0.f, 0.f, 0.f, 0.f, 0.f, 0.f, 0.f, 0.f};
#pragma unroll
  for (int k = 0; k < 9; ++k) {
    const u16* vr = (k < 8) ? (kvh + (size_t)(b0 * 8 + k) * 1024 + 512 + off)
                            : (yr + 1024 + off);
    float vv[8]; ld8bf(vr, vv);
    const float wk = lg[k] * inv;
#pragma unroll
    for (int t = 0; t < 8; ++t) c[t] += wk * vv[t];
  }
  int4 o;
  o.x = pk2(c[0], c[1]); o.y = pk2(c[2], c[3]);
  o.z = pk2(c[4], c[5]); o.w = pk2(c[6], c[7]);
  *(int4*)(ctxh + (size_t)b0 * 512 + off) = o;
}

// ---------------------------------------------------------------------------
// out = ctxh @ Wot + bo   (fp32 out; 2048x512x512)
// ---------------------------------------------------------------------------
__global__ __launch_bounds__(256) void bgemm_out(
    const u16* __restrict__ ctxh, const u16* __restrict__ Wot,
    float* __restrict__ out, const float* __restrict__ bo) {
  __shared__ u16 As[4096];
  __shared__ u16 Bs[4096];
  const int tid = threadIdx.x, lane = tid & 63, w = tid >> 6;
  const int rm = blockIdx.y << 7, cn = blockIdx.x << 7;
  const int srow = tid >> 2, skoff = (tid & 3) << 3;
  const u16* a0 = ctxh + (size_t)(rm + srow) * 512 + skoff;
  const u16* a1 = a0 + (size_t)64 * 512;
  const u16* b0 = Wot + (size_t)(cn + srow) * 512 + skoff;
  const u16* b1 = b0 + (size_t)64 * 512;
  u16* aD0 = As + (w << 9); u16* aD1 = As + 2048 + (w << 9);
  u16* bD0 = Bs + (w << 9); u16* bD1 = Bs + 2048 + (w << 9);
  const int arb = ((((w >> 1) << 6) + (lane & 15)) << 5) + ((lane >> 4) << 3);
  const int brb = ((((w & 1) << 6) + (lane & 15)) << 5) + ((lane >> 4) << 3);
  f32x4 acc[4][4];
#pragma unroll
  for (int i = 0; i < 4; ++i)
#pragma unroll
    for (int j = 0; j < 4; ++j) acc[i][j] = (f32x4){0.f, 0.f, 0.f, 0.f};
  for (int kt = 0; kt < 16; ++kt) {
    const int ko = kt << 5;
    if (kt) __syncthreads();
    gld16(a0 + ko, aD0); gld16(a1 + ko, aD1);
    gld16(b0 + ko, bD0); gld16(b1 + ko, bD1);
    __syncthreads();
    bf16x8 av[4], bv[4];
#pragma unroll
    for (int i = 0; i < 4; ++i) av[i] = *(const bf16x8*)(As + arb + (i << 9));
#pragma unroll
    for (int j = 0; j < 4; ++j) bv[j] = *(const bf16x8*)(Bs + brb + (j << 9));
#pragma unroll
    for (int i = 0; i < 4; ++i)
#pragma unroll
      for (int j = 0; j < 4; ++j)
        acc[i][j] = __builtin_amdgcn_mfma_f32_16x16x32_bf16(av[i], bv[j], acc[i][j], 0, 0, 0);
  }
  const int row0 = rm + ((w >> 1) << 6) + ((lane >> 4) << 2);
  const int col0 = cn + ((w & 1) << 6) + (lane & 15);
  float bc[4];
#pragma unroll
  for (int j = 0; j < 4; ++j) bc[j] = bo[col0 + (j << 4)];
#pragma unroll
  for (int j = 0; j < 4; ++j)
#pragma unroll
    for (int i = 0; i < 4; ++i)
#pragma unroll
      for (int r = 0; r < 4; ++r)
        out[(size_t)(row0 + (i << 4) + r) * 512 + col0 + (j << 4)] = acc[i][j][r] + bc[j];
}

// ---------------------------------------------------------------------------
extern "C" void kernel_launch(void* const* d_in, const int* in_sizes, int n_in,
                              void* d_out, int out_size, void* d_ws, size_t ws_size,
                              hipStream_t stream) {
  const float* hidden = (const float*)d_in[0];
  const float* cached = (const float*)d_in[1];
  const float* Wq = (const float*)d_in[2];
  const float* Wk = (const float*)d_in[3];
  const float* Wv = (const float*)d_in[4];
  const float* Wo = (const float*)d_in[5];
  const float* bo = (const float*)d_in[6];
  const float* W1 = (const float*)d_in[7];
  const float* b1 = (const float*)d_in[8];
  const float* W2 = (const float*)d_in[9];
  const float* b2 = (const float*)d_in[10];
  const float* pe = (const float*)d_in[11];

  float* ws = (float*)d_ws;
  float* Wqk = ws;                          // 512*512 f32
  float* qkb = Wqk + 262144;                // 2048*512 f32
  float* sgv = qkb + 1048576;               // 16384*2 f32
  u16* Wqkvt = (u16*)(sgv + 32768);         // [1536][512]
  u16* W1t   = Wqkvt + 786432;              // [256][1536]
  u16* W2t   = W1t + 393216;                // [1024][256]
  u16* Wot   = W2t + 262144;                // [512][512]
  u16* xh    = Wot + 262144;                // [2048][512]
  u16* gsel  = xh + 1048576;                // [16384][512]
  u16* Yh    = gsel + 8388608;              // [2048][1536]  [q|k_now|v_now]
  u16* kvh   = Yh + 3145728;                // [16384][1024] [k_sel|v_sel]
  u16* hb    = kvh + 16777216;              // [16384][256]
  u16* ctxh  = hb + 4194304;                // [2048][512]
  float* out = (float*)d_out;
  (void)in_sizes; (void)n_in; (void)out_size; (void)ws_size;

  prep_all<<<dim3(1920), 256, 0, stream>>>(Wq, Wk, Wv, W1, W2, Wo,
                                           Wqkvt, W1t, W2t, Wot, Wqk);
  qk_gemm<<<dim3(8, 32), 256, 0, stream>>>(hidden, Wqk, qkb, pe);
  score_topk_gather<<<dim3(2048), 256, 0, stream>>>(qkb, cached, pe, hidden, xh, gsel);
  bgemm_fused1<<<dim3(1216), 256, 0, stream>>>(gsel, xh, Wqkvt, kvh, Yh);
  mlp1_sg<<<dim3(256), 256, 0, stream>>>(Yh, kvh, W1t, b1, W2, b2, hb, sgv);
  bgemm_delta<<<dim3(8, 128), 256, 0, stream>>>(hb, W2t, kvh, b2, sgv);
  attn2<<<dim3(512), 256, 0, stream>>>(Yh, kvh, ctxh);
  bgemm_out<<<dim3(4, 16), 256, 0, stream>>>(ctxh, Wot, out, bo);
}